// Round 1
// 615.659 us; speedup vs baseline: 1.0289x; 1.0289x over previous
//
#include <hip/hip_runtime.h>

// Problem constants (match reference setup_inputs)
constexpr int N_NODES = 50000;
constexpr int N_EDGES = 800000;
constexpr int N_ETOT  = N_EDGES + N_NODES;   // with self loops
constexpr int HID     = 128;
constexpr int HEADS   = 4;
constexpr int ED      = 12;
constexpr int LAYERS  = 4;
constexpr float BN_EPS = 1e-5f;
constexpr int SCAN_BLK = (N_NODES + 255) / 256;   // 196
constexpr int EB = (N_ETOT + 255) / 256;          // 3321 edge blocks
constexpr int GB = (N_NODES + 63) / 64;           // 782 gemm blocks
constexpr int WB = (LAYERS * HID * HID + 255) / 256;  // 256 packW blocks

typedef __attribute__((ext_vector_type(8))) short short8;
typedef __attribute__((ext_vector_type(4))) float floatx4;

__device__ inline unsigned bf16pair(float a, float b) {
    unsigned ua = __float_as_uint(a), ub = __float_as_uint(b);
    ua = (ua + 0x7FFFu + ((ua >> 16) & 1u)) >> 16;
    ub = (ub + 0x7FFFu + ((ub >> 16) & 1u)) >> 16;
    return ua | (ub << 16);
}

// ---------------------------------------------------------------------------
// pre1: [hist+rank | eamean | packW] — independent preamble work, one dispatch.
// The hist atomic now RETURNS the per-destination rank of each edge; the rank
// write is coalesced (4B/edge). This makes pre3's scatter atomic-free.
// ---------------------------------------------------------------------------
__launch_bounds__(256)
__global__ void pre1_kernel(const int* __restrict__ dst, int* __restrict__ hist,
                            int* __restrict__ rank,
                            const float* __restrict__ ea, float* __restrict__ easum,
                            const float* __restrict__ W, unsigned short* __restrict__ wb) {
    __shared__ float ls[12];
    int bid = blockIdx.x, t = threadIdx.x;
    if (bid < EB) {
        int e = bid * 256 + t;
        if (e < N_ETOT) {
            int d = (e < N_EDGES) ? dst[e] : (e - N_EDGES);
            rank[e] = atomicAdd(&hist[d], 1);
        }
    } else if (bid < EB + 256) {
        int b2 = bid - EB;
        if (t < 12) ls[t] = 0.f;
        __syncthreads();
        float loc[12];
#pragma unroll
        for (int d = 0; d < 12; d++) loc[d] = 0.f;
        for (int e = b2 * 256 + t; e < N_EDGES; e += 256 * 256) {
            const float* er = ea + (size_t)e * ED;
#pragma unroll
            for (int d = 0; d < 12; d++) loc[d] += er[d];
        }
#pragma unroll
        for (int d = 0; d < 12; d++) atomicAdd(&ls[d], loc[d]);
        __syncthreads();
        if (t < 12) atomicAdd(&easum[t], ls[t]);
    } else {
        int idx = (bid - EB - 256) * 256 + t;
        if (idx < LAYERS * HID * HID) {
            int l = idx >> 14;
            int k = (idx >> 7) & 127;
            int n = idx & 127;
            unsigned u = __float_as_uint(W[idx]);
            u = (u + 0x7FFFu + ((u >> 16) & 1u)) >> 16;
            int kt = k >> 5, q = (k & 31) >> 3, j = k & 7;
            int nt = n >> 4, c = n & 15;
            int lane = q * 16 + c;
            wb[(size_t)l * 16384 + ((size_t)(kt * 8 + nt) * 64 + lane) * 8 + j] =
                (unsigned short)u;
        }
    }
}

__global__ void blocksum_kernel(const int* __restrict__ hist, int* __restrict__ bsum) {
    __shared__ int sd[256];
    int t = threadIdx.x;
    int n = blockIdx.x * 256 + t;
    sd[t] = (n < N_NODES) ? hist[n] : 0;
    __syncthreads();
#pragma unroll
    for (int off = 128; off; off >>= 1) {
        if (t < off) sd[t] += sd[t + off];
        __syncthreads();
    }
    if (t == 0) bsum[blockIdx.x] = sd[0];
}

// ---------------------------------------------------------------------------
// pre2: [bscan | prep] — block 0 scans block sums; block 1 folds We/att_edge.
// ---------------------------------------------------------------------------
__launch_bounds__(256)
__global__ void pre2_kernel(const int* __restrict__ bsum, int* __restrict__ boff,
                            int* __restrict__ rowp, const float* __restrict__ easum,
                            const float* __restrict__ We, const float* __restrict__ att_edge,
                            float* __restrict__ wea_all, float* __restrict__ aloop) {
    int t = threadIdx.x;
    if (blockIdx.x == 0) {
        __shared__ int sd[256];
        int v = (t < SCAN_BLK) ? bsum[t] : 0;
        sd[t] = v;
        __syncthreads();
#pragma unroll
        for (int off = 1; off < 256; off <<= 1) {
            int u = (t >= off) ? sd[t - off] : 0;
            __syncthreads();
            sd[t] += u;
            __syncthreads();
        }
        if (t < SCAN_BLK) boff[t] = sd[t] - v;
        if (t == 255) rowp[N_NODES] = sd[255];
    } else {
        __shared__ float em[12];
        __shared__ float weash[LAYERS * ED * HEADS];
        if (t < 12) em[t] = easum[t] / (float)N_EDGES;
        if (t < LAYERS * ED * HEADS) {
            int l = t / (ED * HEADS);
            int r = t % (ED * HEADS);
            int d = r / HEADS;
            int h = r % HEADS;
            float sum = 0.f;
#pragma unroll
            for (int c = 0; c < 32; c++)
                sum += We[((size_t)(l * ED + d)) * HID + h * 32 + c] *
                       att_edge[(l * HEADS + h) * 32 + c];
            wea_all[t] = sum;
            weash[t] = sum;
        }
        __syncthreads();
        if (t < LAYERS * HEADS) {
            int l = t / HEADS, h = t % HEADS;
            float s = 0.f;
#pragma unroll
            for (int d = 0; d < 12; d++) s += em[d] * weash[l * ED * HEADS + d * HEADS + h];
            aloop[t] = s;
        }
    }
}

__global__ void rowp_kernel(const int* __restrict__ hist, const int* __restrict__ boff,
                            int* __restrict__ rowp) {
    __shared__ int sd[256];
    int t = threadIdx.x;
    int n = blockIdx.x * 256 + t;
    int v = (n < N_NODES) ? hist[n] : 0;
    sd[t] = v;
    __syncthreads();
#pragma unroll
    for (int off = 1; off < 256; off <<= 1) {
        int u = (t >= off) ? sd[t - off] : 0;
        __syncthreads();
        sd[t] += u;
        __syncthreads();
    }
    if (n < N_NODES) {
        int excl = sd[t] - v + boff[blockIdx.x];
        rowp[n] = excl;
    }
}

// ---------------------------------------------------------------------------
// pre3: [scatter | gemm0] — scatter is now atomic-free: pos = rowp[d]+rank[e]
// (rank captured in pre1's histogram atomic). Remaining cost is the random
// 8B line-allocate store; gemm0's compute overlaps it.
// ---------------------------------------------------------------------------
__launch_bounds__(256)
__global__ void pre3_kernel(const int* __restrict__ src, const int* __restrict__ dst,
                            const int* __restrict__ rank, const int* __restrict__ rowp,
                            int2* __restrict__ csr,
                            const float* __restrict__ A, const float* __restrict__ B,
                            const float* __restrict__ bias, float* __restrict__ C,
                            unsigned* __restrict__ Cb) {
    __shared__ float Bs[64 * 128];
    int t = threadIdx.x;
    if (blockIdx.x < EB) {
        int e = blockIdx.x * 256 + t;
        if (e >= N_ETOT) return;
        int s, d;
        if (e < N_EDGES) { s = src[e]; d = dst[e]; }
        else             { s = d = e - N_EDGES; }
        int pos = rowp[d] + rank[e];
        csr[pos] = make_int2(s, e);
        return;
    }
    // ---- gemm0: h = relu(x @ Wp + bp), dual f32/bf16 out ----
    constexpr int K = 64;
    int bid = blockIdx.x - EB;
    const float4* B4 = (const float4*)B;
    float4* Bs4 = (float4*)Bs;
#pragma unroll
    for (int i = t; i < K * 32; i += 256) Bs4[i] = B4[i];
    __syncthreads();

    int c0 = (t & 15) * 8;
    int r0 = (t >> 4) * 4;
    int rbase = bid * 64 + r0;

    float acc[4][8];
#pragma unroll
    for (int j = 0; j < 4; j++)
#pragma unroll
        for (int c = 0; c < 8; c++) acc[j][c] = 0.f;

    const float4* A4 = (const float4*)A;
    int rg[4];
#pragma unroll
    for (int j = 0; j < 4; j++) rg[j] = min(rbase + j, N_NODES - 1);

    for (int kk = 0; kk < K; kk += 4) {
        float4 av[4];
#pragma unroll
        for (int j = 0; j < 4; j++) av[j] = A4[(size_t)rg[j] * (K / 4) + (kk >> 2)];
        float a_arr[4][4];
#pragma unroll
        for (int j = 0; j < 4; j++) {
            a_arr[j][0] = av[j].x; a_arr[j][1] = av[j].y;
            a_arr[j][2] = av[j].z; a_arr[j][3] = av[j].w;
        }
#pragma unroll
        for (int jj = 0; jj < 4; jj++) {
            float4 b0 = Bs4[(kk + jj) * 32 + (c0 >> 2)];
            float4 b1 = Bs4[(kk + jj) * 32 + (c0 >> 2) + 1];
#pragma unroll
            for (int j = 0; j < 4; j++) {
                float a = a_arr[j][jj];
                acc[j][0] += a * b0.x; acc[j][1] += a * b0.y;
                acc[j][2] += a * b0.z; acc[j][3] += a * b0.w;
                acc[j][4] += a * b1.x; acc[j][5] += a * b1.y;
                acc[j][6] += a * b1.z; acc[j][7] += a * b1.w;
            }
        }
    }

#pragma unroll
    for (int j = 0; j < 4; j++) {
        int r = rbase + j;
        if (r < N_NODES) {
            float o[8];
#pragma unroll
            for (int c = 0; c < 8; c++) o[c] = fmaxf(acc[j][c] + bias[c0 + c], 0.f);
            ((float4*)(C + (size_t)r * 128 + c0))[0] = make_float4(o[0], o[1], o[2], o[3]);
            ((float4*)(C + (size_t)r * 128 + c0 + 4))[0] = make_float4(o[4], o[5], o[6], o[7]);
            uint4 pk;
            pk.x = bf16pair(o[0], o[1]); pk.y = bf16pair(o[2], o[3]);
            pk.z = bf16pair(o[4], o[5]); pk.w = bf16pair(o[6], o[7]);
            ((uint4*)(Cb + (size_t)r * 64 + (c0 >> 1)))[0] = pk;
        }
    }
}

// ---------------------------------------------------------------------------
// pre4: [aedgep | gemm_mfma layer 0]. aedgep: per-edge attention terms for all
// layers in CSR order (bf16x4); gemm: plain MFMA projection reading hAb.
// ---------------------------------------------------------------------------
__launch_bounds__(256)
__global__ void pre4_kernel(const int2* __restrict__ csr, const float* __restrict__ ea,
                            const float* __restrict__ wea_all, const float* __restrict__ aloop,
                            uint2* __restrict__ aecsr,
                            const unsigned short* __restrict__ hAb,
                            const unsigned short* __restrict__ wb,
                            const float* __restrict__ att_s, const float* __restrict__ att_d,
                            unsigned* __restrict__ xpb,
                            float* __restrict__ asrc, float* __restrict__ adst) {
    __shared__ float smem[4 * 16 * 129];   // 33 KB, shared by both branches
    int t = threadIdx.x;
    if (blockIdx.x < EB) {
        float* wsh = smem;            // 192
        float* lsh = smem + 192;      // 16
        if (t < LAYERS * ED * HEADS) wsh[t] = wea_all[t];
        if (t < LAYERS * HEADS) lsh[t] = aloop[t];
        __syncthreads();
        int i = blockIdx.x * 256 + t;
        if (i >= N_ETOT) return;
        int e = csr[i].y;
        float a[LAYERS][4];
        if (e < N_EDGES) {
            float er[12];
            const float* ep = ea + (size_t)e * ED;
#pragma unroll
            for (int d = 0; d < 12; d++) er[d] = ep[d];
#pragma unroll
            for (int l = 0; l < LAYERS; l++)
#pragma unroll
                for (int h = 0; h < 4; h++) {
                    float s = 0.f;
#pragma unroll
                    for (int d = 0; d < 12; d++) s += er[d] * wsh[l * 48 + d * 4 + h];
                    a[l][h] = s;
                }
        } else {
#pragma unroll
            for (int l = 0; l < LAYERS; l++)
#pragma unroll
                for (int h = 0; h < 4; h++) a[l][h] = lsh[l * 4 + h];
        }
#pragma unroll
        for (int l = 0; l < LAYERS; l++)
            aecsr[(size_t)l * N_ETOT + i] =
                make_uint2(bf16pair(a[l][0], a[l][1]), bf16pair(a[l][2], a[l][3]));
        return;
    }
    // ---- plain MFMA projection (layer 0), A from hAb ----
    int bid = blockIdx.x - EB;
    float (*lds)[16][129] = (float (*)[16][129])smem;
    int w = t >> 6, lane = t & 63;
    int rbase = bid * 64 + w * 16;
    int mrow = lane & 15, quad = lane >> 4;

    floatx4 acc[8];
#pragma unroll
    for (int nt = 0; nt < 8; nt++) acc[nt] = (floatx4){0.f, 0.f, 0.f, 0.f};

    int arow = min(rbase + mrow, N_NODES - 1);
    const short8* wb8 = (const short8*)wb;
#pragma unroll
    for (int kt = 0; kt < 4; kt++) {
        short8 afrag = *(const short8*)(hAb + (size_t)arow * 128 + kt * 32 + quad * 8);
#pragma unroll
        for (int nt = 0; nt < 8; nt++) {
            short8 bfrag = wb8[(kt * 8 + nt) * 64 + lane];
            acc[nt] = __builtin_amdgcn_mfma_f32_16x16x32_bf16(afrag, bfrag, acc[nt], 0, 0, 0);
        }
    }
#pragma unroll
    for (int nt = 0; nt < 8; nt++)
#pragma unroll
        for (int rr = 0; rr < 4; rr++)
            lds[w][quad * 4 + rr][nt * 16 + mrow] = acc[nt][rr];

    int row = lane >> 2, h = lane & 3;
    int r = rbase + row;
    float vals[32];
    float ps = 0.f, pd = 0.f;
#pragma unroll
    for (int c = 0; c < 32; c++) {
        float v = lds[w][row][h * 32 + c];
        vals[c] = v;
        ps += v * att_s[h * 32 + c];
        pd += v * att_d[h * 32 + c];
    }
    if (r < N_NODES) {
        unsigned* dstp = xpb + (size_t)r * 64 + h * 16;
#pragma unroll
        for (int qq = 0; qq < 4; qq++) {
            uint4 o;
            o.x = bf16pair(vals[qq * 8 + 0], vals[qq * 8 + 1]);
            o.y = bf16pair(vals[qq * 8 + 2], vals[qq * 8 + 3]);
            o.z = bf16pair(vals[qq * 8 + 4], vals[qq * 8 + 5]);
            o.w = bf16pair(vals[qq * 8 + 6], vals[qq * 8 + 7]);
            ((uint4*)dstp)[qq] = o;
        }
        asrc[r * 4 + h] = ps;
        adst[r * 4 + h] = pd;
    }
}

// ---------------------------------------------------------------------------
// Fused BN-update + MFMA projection (layers 1..3). Prologue per lane: read
// outb chunk, apply BN(scale/shift from bnsum in LDS) + relu (+ residual hA),
// write new hA (owner lanes only — avoids row-(N-1) clamp race), pack bf16
// A-fragment in registers. Replaces update_kernel + hAb round-trip.
// ---------------------------------------------------------------------------
template <int ADD>
__launch_bounds__(256)
__global__ void gemm_fused_kernel(const float* __restrict__ outb,
                                  const float* __restrict__ bnsum,
                                  const float* __restrict__ bnsum2,
                                  const float* __restrict__ gamma,
                                  const float* __restrict__ beta,
                                  float* __restrict__ hA,
                                  const unsigned short* __restrict__ wb,
                                  const float* __restrict__ att_s,
                                  const float* __restrict__ att_d,
                                  unsigned* __restrict__ xpb,
                                  float* __restrict__ asrc, float* __restrict__ adst) {
    __shared__ float lds[4][16][129];
    __shared__ float sc_s[128], sh_s[128];
    int t = threadIdx.x;
    if (t < 128) {
        float mu = bnsum[t] / (float)N_NODES;
        float var = bnsum2[t] / (float)N_NODES - mu * mu;
        float inv = rsqrtf(var + BN_EPS);
        float g = gamma[t] * inv;
        sc_s[t] = g;
        sh_s[t] = beta[t] - mu * g;
    }
    __syncthreads();

    int w = t >> 6, lane = t & 63;
    int rbase = blockIdx.x * 64 + w * 16;
    int mrow = lane & 15, quad = lane >> 4;
    int arow = rbase + mrow;
    bool owner = arow < N_NODES;
    int ar = min(arow, N_NODES - 1);

    floatx4 acc[8];
#pragma unroll
    for (int nt = 0; nt < 8; nt++) acc[nt] = (floatx4){0.f, 0.f, 0.f, 0.f};

    const short8* wb8 = (const short8*)wb;
#pragma unroll
    for (int kt = 0; kt < 4; kt++) {
        int cb = kt * 32 + quad * 8;
        const float4* ob = (const float4*)(outb + (size_t)ar * 128 + cb);
        float4 o0 = ob[0], o1 = ob[1];
        float v[8];
        v[0] = fmaxf(o0.x * sc_s[cb + 0] + sh_s[cb + 0], 0.f);
        v[1] = fmaxf(o0.y * sc_s[cb + 1] + sh_s[cb + 1], 0.f);
        v[2] = fmaxf(o0.z * sc_s[cb + 2] + sh_s[cb + 2], 0.f);
        v[3] = fmaxf(o0.w * sc_s[cb + 3] + sh_s[cb + 3], 0.f);
        v[4] = fmaxf(o1.x * sc_s[cb + 4] + sh_s[cb + 4], 0.f);
        v[5] = fmaxf(o1.y * sc_s[cb + 5] + sh_s[cb + 5], 0.f);
        v[6] = fmaxf(o1.z * sc_s[cb + 6] + sh_s[cb + 6], 0.f);
        v[7] = fmaxf(o1.w * sc_s[cb + 7] + sh_s[cb + 7], 0.f);
        if (ADD) {
            const float4* hp = (const float4*)(hA + (size_t)ar * 128 + cb);
            float4 h0 = hp[0], h1 = hp[1];
            v[0] += h0.x; v[1] += h0.y; v[2] += h0.z; v[3] += h0.w;
            v[4] += h1.x; v[5] += h1.y; v[6] += h1.z; v[7] += h1.w;
        }
        if (owner) {
            float4* hw = (float4*)(hA + (size_t)ar * 128 + cb);
            hw[0] = make_float4(v[0], v[1], v[2], v[3]);
            hw[1] = make_float4(v[4], v[5], v[6], v[7]);
        }
        uint4 pk;
        pk.x = bf16pair(v[0], v[1]); pk.y = bf16pair(v[2], v[3]);
        pk.z = bf16pair(v[4], v[5]); pk.w = bf16pair(v[6], v[7]);
        short8 afrag = *(short8*)&pk;
#pragma unroll
        for (int nt = 0; nt < 8; nt++) {
            short8 bfrag = wb8[(kt * 8 + nt) * 64 + lane];
            acc[nt] = __builtin_amdgcn_mfma_f32_16x16x32_bf16(afrag, bfrag, acc[nt], 0, 0, 0);
        }
    }

#pragma unroll
    for (int nt = 0; nt < 8; nt++)
#pragma unroll
        for (int rr = 0; rr < 4; rr++)
            lds[w][quad * 4 + rr][nt * 16 + mrow] = acc[nt][rr];

    int row = lane >> 2, h = lane & 3;
    int r = rbase + row;
    float vals[32];
    float ps = 0.f, pd = 0.f;
#pragma unroll
    for (int c = 0; c < 32; c++) {
        float v = lds[w][row][h * 32 + c];
        vals[c] = v;
        ps += v * att_s[h * 32 + c];
        pd += v * att_d[h * 32 + c];
    }
    if (r < N_NODES) {
        unsigned* dstp = xpb + (size_t)r * 64 + h * 16;
#pragma unroll
        for (int qq = 0; qq < 4; qq++) {
            uint4 o;
            o.x = bf16pair(vals[qq * 8 + 0], vals[qq * 8 + 1]);
            o.y = bf16pair(vals[qq * 8 + 2], vals[qq * 8 + 3]);
            o.z = bf16pair(vals[qq * 8 + 4], vals[qq * 8 + 5]);
            o.w = bf16pair(vals[qq * 8 + 6], vals[qq * 8 + 7]);
            ((uint4*)dstp)[qq] = o;
        }
        asrc[r * 4 + h] = ps;
        adst[r * 4 + h] = pd;
    }
}

// ---------------------------------------------------------------------------
// Single-pass aggregation with on-the-fly softmax weights (see R10 notes).
// ---------------------------------------------------------------------------
__launch_bounds__(256)
__global__ void node_kernel(const uint2* __restrict__ aecsr, const float* __restrict__ asrc,
                            const float* __restrict__ adst, const int* __restrict__ rowp,
                            const int2* __restrict__ csr, const unsigned* __restrict__ xpb,
                            float* __restrict__ out) {
    int gw = (blockIdx.x * blockDim.x + threadIdx.x) >> 6;
    int lane = threadIdx.x & 63;
    if (gw >= N_NODES) return;
    int sub = lane >> 4;
    int sl  = lane & 15;
    int h   = sl >> 2;
    int beg = rowp[gw], end = rowp[gw + 1];
    const uint4* xp4 = (const uint4*)xpb;
    float adh = adst[gw * 4 + h];

    float a[8];
#pragma unroll
    for (int c = 0; c < 8; c++) a[c] = 0.f;
    float den = 0.f;

#define PROC(JJ)                                                                 \
    {                                                                            \
        int2 se = csr[JJ];                                                       \
        uint2 ae = aecsr[JJ];                                                    \
        unsigned aw = (h & 2) ? ae.y : ae.x;                                     \
        float aeh = __uint_as_float((h & 1) ? (aw & 0xFFFF0000u) : (aw << 16));  \
        float ash = asrc[se.x * 4 + h];                                          \
        uint4 v = xp4[(size_t)se.x * 16 + sl];                                   \
        float lg = ash + adh + aeh;                                              \
        lg = (lg > 0.f) ? lg : 0.2f * lg;                                        \
        float ex = __expf(fminf(lg, 60.f));                                      \
        a[0] += ex * __uint_as_float(v.x << 16);                                 \
        a[1] += ex * __uint_as_float(v.x & 0xFFFF0000u);                         \
        a[2] += ex * __uint_as_float(v.y << 16);                                 \
        a[3] += ex * __uint_as_float(v.y & 0xFFFF0000u);                         \
        a[4] += ex * __uint_as_float(v.z << 16);                                 \
        a[5] += ex * __uint_as_float(v.z & 0xFFFF0000u);                         \
        a[6] += ex * __uint_as_float(v.w << 16);                                 \
        a[7] += ex * __uint_as_float(v.w & 0xFFFF0000u);                         \
        den += ex;                                                               \
    }

    int j = beg + sub;
    for (; j + 12 < end; j += 16) {
        PROC(j); PROC(j + 4); PROC(j + 8); PROC(j + 12);
    }
    for (; j < end; j += 4) PROC(j);
#undef PROC

#pragma unroll
    for (int c = 0; c < 8; c++) {
        a[c] += __shfl_xor(a[c], 16);
        a[c] += __shfl_xor(a[c], 32);
    }
    den += __shfl_xor(den, 16);
    den += __shfl_xor(den, 32);
    float inv = 1.0f / den;
    if (sub == 0) {
        float* op = out + (size_t)gw * 128 + sl * 8;
        ((float4*)op)[0] = make_float4(a[0] * inv, a[1] * inv, a[2] * inv, a[3] * inv);
        ((float4*)op)[1] = make_float4(a[4] * inv, a[5] * inv, a[6] * inv, a[7] * inv);
    }
}

// ---------------------------------------------------------------------------
// BatchNorm statistics; final-layer standalone update (writes outp).
// ---------------------------------------------------------------------------
__launch_bounds__(256)
__global__ void bnstats_kernel(const float* __restrict__ h, float* __restrict__ bnsum,
                               float* __restrict__ bnsum2) {
    __shared__ float ls[256], ls2[256];
    int t = threadIdx.x;
    int c = t & 127, half = t >> 7;
    int r0 = blockIdx.x * 128;
    float s = 0.f, s2 = 0.f;
    int rend = min(r0 + 128, N_NODES);
    for (int r = r0 + half; r < rend; r += 2) {
        float v = h[(size_t)r * 128 + c];
        s += v; s2 += v * v;
    }
    ls[t] = s; ls2[t] = s2;
    __syncthreads();
    if (half == 0) {
        s += ls[t + 128]; s2 += ls2[t + 128];
        atomicAdd(&bnsum[c], s);
        atomicAdd(&bnsum2[c], s2);
    }
}

__launch_bounds__(256)
__global__ void finalupd_kernel(const float* __restrict__ outb, const float* __restrict__ bnsum,
                                const float* __restrict__ bnsum2, const float* __restrict__ gamma,
                                const float* __restrict__ beta, const float* __restrict__ hA,
                                float* __restrict__ dst) {
    __shared__ float sc_s[128], sh_s[128];
    int t = threadIdx.x;
    if (t < 128) {
        float mu = bnsum[t] / (float)N_NODES;
        float var = bnsum2[t] / (float)N_NODES - mu * mu;
        float inv = rsqrtf(var + BN_EPS);
        float g = gamma[t] * inv;
        sc_s[t] = g;
        sh_s[t] = beta[t] - mu * g;
    }
    __syncthreads();
    int i = blockIdx.x * blockDim.x + t;
    if (i >= N_NODES * 32) return;
    int c4 = (i & 31) * 4;
    float4 o = ((const float4*)outb)[i];
    float4 hh = ((const float4*)hA)[i];
    float4 v;
    v.x = fmaxf(o.x * sc_s[c4 + 0] + sh_s[c4 + 0], 0.f) + hh.x;
    v.y = fmaxf(o.y * sc_s[c4 + 1] + sh_s[c4 + 1], 0.f) + hh.y;
    v.z = fmaxf(o.z * sc_s[c4 + 2] + sh_s[c4 + 2], 0.f) + hh.z;
    v.w = fmaxf(o.w * sc_s[c4 + 3] + sh_s[c4 + 3], 0.f) + hh.w;
    ((float4*)dst)[i] = v;
}

// ---------------------------------------------------------------------------
extern "C" void kernel_launch(void* const* d_in, const int* in_sizes, int n_in,
                              void* d_out, int out_size, void* d_ws, size_t ws_size,
                              hipStream_t stream) {
    const float* x          = (const float*)d_in[0];
    const int*   edge_index = (const int*)d_in[1];
    const float* edge_attr  = (const float*)d_in[2];
    const float* Wp         = (const float*)d_in[3];
    const float* bp         = (const float*)d_in[4];
    const float* W          = (const float*)d_in[5];
    const float* We         = (const float*)d_in[6];
    const float* att_src    = (const float*)d_in[7];
    const float* att_dst    = (const float*)d_in[8];
    const float* att_edge   = (const float*)d_in[9];
    // d_in[10] bias: absorbed exactly by training-mode BN -> skipped
    const float* gamma      = (const float*)d_in[11];
    const float* beta       = (const float*)d_in[12];
    float* outp = (float*)d_out;

    const int* ei_src = edge_index;
    const int* ei_dst = edge_index + N_EDGES;

    char* p = (char*)d_ws;
    auto alloc = [&](size_t nbytes) {
        char* r = p;
        p += (nbytes + 255) & ~(size_t)255;
        return r;
    };
    // zero-initialized region: hist | easum | bnsum(4 layers x 256)
    int*   hist     = (int*)alloc((size_t)N_NODES * 4);
    float* easum    = (float*)alloc(16 * 4);
    float* bnsumall = (float*)alloc((size_t)LAYERS * 256 * 4);
    size_t zero_bytes = (char*)(bnsumall + LAYERS * 256) - (char*)hist;

    float* hA       = (float*)alloc((size_t)N_NODES * 128 * 4);
    unsigned* hAb   = (unsigned*)alloc((size_t)N_NODES * 64 * 4);   // bf16x2 (layer-0 A feed)
    unsigned* xpb   = (unsigned*)alloc((size_t)N_NODES * 64 * 4);   // bf16x2 gather payload
    float* outb     = (float*)alloc((size_t)N_NODES * 128 * 4);
    float* asrc     = (float*)alloc((size_t)N_NODES * 4 * 4);
    float* adst     = (float*)alloc((size_t)N_NODES * 4 * 4);
    float* wea_all  = (float*)alloc((LAYERS * 48 + 16) * 4);
    float* aloop    = wea_all + LAYERS * 48;
    unsigned short* wb = (unsigned short*)alloc((size_t)LAYERS * 16384 * 2);
    int* rowp       = (int*)alloc(((size_t)N_NODES + 1) * 4);
    int* rankbuf    = (int*)alloc((size_t)N_ETOT * 4);
    int2* csr       = (int2*)alloc((size_t)N_ETOT * 8);
    uint2* aecsr    = (uint2*)alloc((size_t)LAYERS * N_ETOT * 8);
    int* bsum       = (int*)alloc(256 * 4);
    int* boff       = (int*)alloc(256 * 4);

    (void)hipMemsetAsync(hist, 0, zero_bytes, stream);

    // ---- preamble: CSR build + folded matrices + W pack, fused ----
    pre1_kernel<<<EB + 256 + WB, 256, 0, stream>>>(ei_dst, hist, rankbuf, edge_attr, easum, W, wb);
    blocksum_kernel<<<SCAN_BLK, 256, 0, stream>>>(hist, bsum);
    pre2_kernel<<<2, 256, 0, stream>>>(bsum, boff, rowp, easum, We, att_edge, wea_all, aloop);
    rowp_kernel<<<SCAN_BLK, 256, 0, stream>>>(hist, boff, rowp);
    pre3_kernel<<<EB + GB, 256, 0, stream>>>(ei_src, ei_dst, rankbuf, rowp, csr, x, Wp, bp, hA, hAb);
    pre4_kernel<<<EB + GB, 256, 0, stream>>>(csr, edge_attr, wea_all, aloop, aecsr,
                                             (const unsigned short*)hAb, wb,
                                             att_src, att_dst, xpb, asrc, adst);

    for (int l = 0; l < LAYERS; l++) {
        float* bnsum  = bnsumall + l * 256;
        float* bnsum2 = bnsum + 128;
        node_kernel<<<(N_NODES + 3) / 4, 256, 0, stream>>>(
            aecsr + (size_t)l * N_ETOT, asrc, adst, rowp, csr, xpb, outb);
        bnstats_kernel<<<(N_NODES + 127) / 128, 256, 0, stream>>>(outb, bnsum, bnsum2);
        if (l < LAYERS - 1) {
            // fused: h_{l+1} = relu(bn_l(outb)) (+ hA if l>0) -> hA, A-frag in-reg
            if (l == 0)
                gemm_fused_kernel<0><<<GB, 256, 0, stream>>>(
                    outb, bnsum, bnsum2, gamma + l * 128, beta + l * 128, hA,
                    wb + (size_t)(l + 1) * 16384, att_src + (l + 1) * 128,
                    att_dst + (l + 1) * 128, xpb, asrc, adst);
            else
                gemm_fused_kernel<1><<<GB, 256, 0, stream>>>(
                    outb, bnsum, bnsum2, gamma + l * 128, beta + l * 128, hA,
                    wb + (size_t)(l + 1) * 16384, att_src + (l + 1) * 128,
                    att_dst + (l + 1) * 128, xpb, asrc, adst);
        } else {
            finalupd_kernel<<<(N_NODES * 32 + 255) / 256, 256, 0, stream>>>(
                outb, bnsum, bnsum2, gamma + l * 128, beta + l * 128, hA, outp);
        }
    }
}

// Round 2
// 597.463 us; speedup vs baseline: 1.0603x; 1.0305x over previous
//
#include <hip/hip_runtime.h>

// Problem constants (match reference setup_inputs)
constexpr int N_NODES = 50000;
constexpr int N_EDGES = 800000;
constexpr int N_ETOT  = N_EDGES + N_NODES;   // with self loops
constexpr int HID     = 128;
constexpr int HEADS   = 4;
constexpr int ED      = 12;
constexpr int LAYERS  = 4;
constexpr float BN_EPS = 1e-5f;
constexpr int R_REP = 4;                          // histogram replication factor
constexpr int RN = N_NODES * R_REP;               // 200000 flattened (d,r) bins
constexpr int SB2 = (RN + 255) / 256;             // 782 scan blocks
constexpr int EB = (N_ETOT + 255) / 256;          // 3321 edge blocks
constexpr int GB = (N_NODES + 63) / 64;           // 782 gemm blocks
constexpr int WB = (LAYERS * HID * HID + 255) / 256;  // 256 packW blocks

typedef __attribute__((ext_vector_type(8))) short short8;
typedef __attribute__((ext_vector_type(4))) float floatx4;

__device__ inline unsigned bf16pair(float a, float b) {
    unsigned ua = __float_as_uint(a), ub = __float_as_uint(b);
    ua = (ua + 0x7FFFu + ((ua >> 16) & 1u)) >> 16;
    ub = (ub + 0x7FFFu + ((ub >> 16) & 1u)) >> 16;
    return ua | (ub << 16);
}

// ---------------------------------------------------------------------------
// pre1: [gemm0 | hist+rank | eamean | packW] — gemm0 (x@Wp, no deps) rides
// under the histogram atomics. Histogram is 4-way replicated, replica-major
// (hist2[r*N+d]) so replicas of one node sit on different 64B lines: spreads
// the per-line serialized RMW ping-pong 4x.
// ---------------------------------------------------------------------------
__launch_bounds__(256)
__global__ void pre1_kernel(const int* __restrict__ dst, int* __restrict__ hist2,
                            int* __restrict__ rank,
                            const float* __restrict__ ea, float* __restrict__ easum,
                            const float* __restrict__ W, unsigned short* __restrict__ wb,
                            const float* __restrict__ A, const float* __restrict__ B,
                            const float* __restrict__ bias, float* __restrict__ C,
                            unsigned* __restrict__ Cb) {
    __shared__ float smem[64 * 128];   // gemm0 Bs; eamean uses first 12 floats
    int bid = blockIdx.x, t = threadIdx.x;
    if (bid < GB) {
        // ---- gemm0: h = relu(x @ Wp + bp), dual f32/bf16 out ----
        constexpr int K = 64;
        const float4* B4 = (const float4*)B;
        float4* Bs4 = (float4*)smem;
#pragma unroll
        for (int i = t; i < K * 32; i += 256) Bs4[i] = B4[i];
        __syncthreads();

        int c0 = (t & 15) * 8;
        int r0 = (t >> 4) * 4;
        int rbase = bid * 64 + r0;

        float acc[4][8];
#pragma unroll
        for (int j = 0; j < 4; j++)
#pragma unroll
            for (int c = 0; c < 8; c++) acc[j][c] = 0.f;

        const float4* A4 = (const float4*)A;
        int rg[4];
#pragma unroll
        for (int j = 0; j < 4; j++) rg[j] = min(rbase + j, N_NODES - 1);

        for (int kk = 0; kk < K; kk += 4) {
            float4 av[4];
#pragma unroll
            for (int j = 0; j < 4; j++) av[j] = A4[(size_t)rg[j] * (K / 4) + (kk >> 2)];
            float a_arr[4][4];
#pragma unroll
            for (int j = 0; j < 4; j++) {
                a_arr[j][0] = av[j].x; a_arr[j][1] = av[j].y;
                a_arr[j][2] = av[j].z; a_arr[j][3] = av[j].w;
            }
#pragma unroll
            for (int jj = 0; jj < 4; jj++) {
                float4 b0 = Bs4[(kk + jj) * 32 + (c0 >> 2)];
                float4 b1 = Bs4[(kk + jj) * 32 + (c0 >> 2) + 1];
#pragma unroll
                for (int j = 0; j < 4; j++) {
                    float a = a_arr[j][jj];
                    acc[j][0] += a * b0.x; acc[j][1] += a * b0.y;
                    acc[j][2] += a * b0.z; acc[j][3] += a * b0.w;
                    acc[j][4] += a * b1.x; acc[j][5] += a * b1.y;
                    acc[j][6] += a * b1.z; acc[j][7] += a * b1.w;
                }
            }
        }

#pragma unroll
        for (int j = 0; j < 4; j++) {
            int r = rbase + j;
            if (r < N_NODES) {
                float o[8];
#pragma unroll
                for (int c = 0; c < 8; c++) o[c] = fmaxf(acc[j][c] + bias[c0 + c], 0.f);
                ((float4*)(C + (size_t)r * 128 + c0))[0] = make_float4(o[0], o[1], o[2], o[3]);
                ((float4*)(C + (size_t)r * 128 + c0 + 4))[0] = make_float4(o[4], o[5], o[6], o[7]);
                uint4 pk;
                pk.x = bf16pair(o[0], o[1]); pk.y = bf16pair(o[2], o[3]);
                pk.z = bf16pair(o[4], o[5]); pk.w = bf16pair(o[6], o[7]);
                ((uint4*)(Cb + (size_t)r * 64 + (c0 >> 1)))[0] = pk;
            }
        }
    } else if (bid < GB + EB) {
        int e = (bid - GB) * 256 + t;
        if (e < N_ETOT) {
            int d = (e < N_EDGES) ? dst[e] : (e - N_EDGES);
            rank[e] = atomicAdd(&hist2[(e & (R_REP - 1)) * N_NODES + d], 1);
        }
    } else if (bid < GB + EB + 256) {
        int b2 = bid - GB - EB;
        float* ls = smem;
        if (t < 12) ls[t] = 0.f;
        __syncthreads();
        float loc[12];
#pragma unroll
        for (int d = 0; d < 12; d++) loc[d] = 0.f;
        for (int e = b2 * 256 + t; e < N_EDGES; e += 256 * 256) {
            const float* er = ea + (size_t)e * ED;
#pragma unroll
            for (int d = 0; d < 12; d++) loc[d] += er[d];
        }
#pragma unroll
        for (int d = 0; d < 12; d++) atomicAdd(&ls[d], loc[d]);
        __syncthreads();
        if (t < 12) atomicAdd(&easum[t], ls[t]);
    } else {
        int idx = (bid - GB - EB - 256) * 256 + t;
        if (idx < LAYERS * HID * HID) {
            int l = idx >> 14;
            int k = (idx >> 7) & 127;
            int n = idx & 127;
            unsigned u = __float_as_uint(W[idx]);
            u = (u + 0x7FFFu + ((u >> 16) & 1u)) >> 16;
            int kt = k >> 5, q = (k & 31) >> 3, j = k & 7;
            int nt = n >> 4, c = n & 15;
            int lane = q * 16 + c;
            wb[(size_t)l * 16384 + ((size_t)(kt * 8 + nt) * 64 + lane) * 8 + j] =
                (unsigned short)u;
        }
    }
}

// blocksum over flattened (d,r) bins: f = d*R + r  ->  hist2[r*N + d]
__global__ void blocksum_kernel(const int* __restrict__ hist2, int* __restrict__ bsum) {
    __shared__ int sd[256];
    int t = threadIdx.x;
    int f = blockIdx.x * 256 + t;
    int v = 0;
    if (f < RN) v = hist2[(f & (R_REP - 1)) * N_NODES + (f >> 2)];
    sd[t] = v;
    __syncthreads();
#pragma unroll
    for (int off = 128; off; off >>= 1) {
        if (t < off) sd[t] += sd[t + off];
        __syncthreads();
    }
    if (t == 0) bsum[blockIdx.x] = sd[0];
}

// ---------------------------------------------------------------------------
// pre2: [bscan | prep] — block 0 scans SB2=782 block sums (4 per thread);
// block 1 folds We/att_edge.
// ---------------------------------------------------------------------------
__launch_bounds__(256)
__global__ void pre2_kernel(const int* __restrict__ bsum, int* __restrict__ boff,
                            int* __restrict__ rowpR, const float* __restrict__ easum,
                            const float* __restrict__ We, const float* __restrict__ att_edge,
                            float* __restrict__ wea_all, float* __restrict__ aloop) {
    int t = threadIdx.x;
    if (blockIdx.x == 0) {
        __shared__ int sd[256];
        int b = 4 * t;
        int v0 = (b + 0 < SB2) ? bsum[b + 0] : 0;
        int v1 = (b + 1 < SB2) ? bsum[b + 1] : 0;
        int v2 = (b + 2 < SB2) ? bsum[b + 2] : 0;
        int v3 = (b + 3 < SB2) ? bsum[b + 3] : 0;
        int tot = v0 + v1 + v2 + v3;
        sd[t] = tot;
        __syncthreads();
#pragma unroll
        for (int off = 1; off < 256; off <<= 1) {
            int u = (t >= off) ? sd[t - off] : 0;
            __syncthreads();
            sd[t] += u;
            __syncthreads();
        }
        int excl = sd[t] - tot;
        if (b + 0 < SB2) boff[b + 0] = excl;
        if (b + 1 < SB2) boff[b + 1] = excl + v0;
        if (b + 2 < SB2) boff[b + 2] = excl + v0 + v1;
        if (b + 3 < SB2) boff[b + 3] = excl + v0 + v1 + v2;
        if (t == 255) rowpR[RN] = sd[255];
    } else {
        __shared__ float em[12];
        __shared__ float weash[LAYERS * ED * HEADS];
        if (t < 12) em[t] = easum[t] / (float)N_EDGES;
        if (t < LAYERS * ED * HEADS) {
            int l = t / (ED * HEADS);
            int r = t % (ED * HEADS);
            int d = r / HEADS;
            int h = r % HEADS;
            float sum = 0.f;
#pragma unroll
            for (int c = 0; c < 32; c++)
                sum += We[((size_t)(l * ED + d)) * HID + h * 32 + c] *
                       att_edge[(l * HEADS + h) * 32 + c];
            wea_all[t] = sum;
            weash[t] = sum;
        }
        __syncthreads();
        if (t < LAYERS * HEADS) {
            int l = t / HEADS, h = t % HEADS;
            float s = 0.f;
#pragma unroll
            for (int d = 0; d < 12; d++) s += em[d] * weash[l * ED * HEADS + d * HEADS + h];
            aloop[t] = s;
        }
    }
}

__global__ void rowp_kernel(const int* __restrict__ hist2, const int* __restrict__ boff,
                            int* __restrict__ rowpR) {
    __shared__ int sd[256];
    int t = threadIdx.x;
    int f = blockIdx.x * 256 + t;
    int v = (f < RN) ? hist2[(f & (R_REP - 1)) * N_NODES + (f >> 2)] : 0;
    sd[t] = v;
    __syncthreads();
#pragma unroll
    for (int off = 1; off < 256; off <<= 1) {
        int u = (t >= off) ? sd[t - off] : 0;
        __syncthreads();
        sd[t] += u;
        __syncthreads();
    }
    if (f < RN) rowpR[f] = sd[t] - v + boff[blockIdx.x];
}

// ---------------------------------------------------------------------------
// pre3: [xp-proj MFMA (layer 0) | scatter]. Scatter is atomic-free:
// pos = rowpR[d*4 + (e&3)] + rank[e]. The ~57us random-line-write floor hides
// under the layer-0 projection.
// ---------------------------------------------------------------------------
__launch_bounds__(256)
__global__ void pre3_kernel(const unsigned short* __restrict__ hAb,
                            const unsigned short* __restrict__ wb,
                            const float* __restrict__ att_s, const float* __restrict__ att_d,
                            unsigned* __restrict__ xpb,
                            float* __restrict__ asrc, float* __restrict__ adst,
                            const int* __restrict__ src, const int* __restrict__ dst,
                            const int* __restrict__ rank, const int* __restrict__ rowpR,
                            int2* __restrict__ csr) {
    __shared__ float smem[4 * 16 * 129];   // 33 KB
    int t = threadIdx.x;
    if (blockIdx.x >= GB) {
        int e = (blockIdx.x - GB) * 256 + t;
        if (e >= N_ETOT) return;
        int s, d;
        if (e < N_EDGES) { s = src[e]; d = dst[e]; }
        else             { s = d = e - N_EDGES; }
        int pos = rowpR[d * R_REP + (e & (R_REP - 1))] + rank[e];
        csr[pos] = make_int2(s, e);
        return;
    }
    // ---- plain MFMA projection (layer 0), A from hAb ----
    int bid = blockIdx.x;
    float (*lds)[16][129] = (float (*)[16][129])smem;
    int w = t >> 6, lane = t & 63;
    int rbase = bid * 64 + w * 16;
    int mrow = lane & 15, quad = lane >> 4;

    floatx4 acc[8];
#pragma unroll
    for (int nt = 0; nt < 8; nt++) acc[nt] = (floatx4){0.f, 0.f, 0.f, 0.f};

    int arow = min(rbase + mrow, N_NODES - 1);
    const short8* wb8 = (const short8*)wb;
#pragma unroll
    for (int kt = 0; kt < 4; kt++) {
        short8 afrag = *(const short8*)(hAb + (size_t)arow * 128 + kt * 32 + quad * 8);
#pragma unroll
        for (int nt = 0; nt < 8; nt++) {
            short8 bfrag = wb8[(kt * 8 + nt) * 64 + lane];
            acc[nt] = __builtin_amdgcn_mfma_f32_16x16x32_bf16(afrag, bfrag, acc[nt], 0, 0, 0);
        }
    }
#pragma unroll
    for (int nt = 0; nt < 8; nt++)
#pragma unroll
        for (int rr = 0; rr < 4; rr++)
            lds[w][quad * 4 + rr][nt * 16 + mrow] = acc[nt][rr];

    int row = lane >> 2, h = lane & 3;
    int r = rbase + row;
    float vals[32];
    float ps = 0.f, pd = 0.f;
#pragma unroll
    for (int c = 0; c < 32; c++) {
        float v = lds[w][row][h * 32 + c];
        vals[c] = v;
        ps += v * att_s[h * 32 + c];
        pd += v * att_d[h * 32 + c];
    }
    if (r < N_NODES) {
        unsigned* dstp = xpb + (size_t)r * 64 + h * 16;
#pragma unroll
        for (int qq = 0; qq < 4; qq++) {
            uint4 o;
            o.x = bf16pair(vals[qq * 8 + 0], vals[qq * 8 + 1]);
            o.y = bf16pair(vals[qq * 8 + 2], vals[qq * 8 + 3]);
            o.z = bf16pair(vals[qq * 8 + 4], vals[qq * 8 + 5]);
            o.w = bf16pair(vals[qq * 8 + 6], vals[qq * 8 + 7]);
            ((uint4*)dstp)[qq] = o;
        }
        asrc[r * 4 + h] = ps;
        adst[r * 4 + h] = pd;
    }
}

// ---------------------------------------------------------------------------
// pre4: aedgep — per-edge attention terms for all layers in CSR order (bf16x4).
// ---------------------------------------------------------------------------
__launch_bounds__(256)
__global__ void pre4_kernel(const int2* __restrict__ csr, const float* __restrict__ ea,
                            const float* __restrict__ wea_all, const float* __restrict__ aloop,
                            uint2* __restrict__ aecsr) {
    __shared__ float wsh[LAYERS * ED * HEADS];
    __shared__ float lsh[LAYERS * HEADS];
    int t = threadIdx.x;
    if (t < LAYERS * ED * HEADS) wsh[t] = wea_all[t];
    if (t < LAYERS * HEADS) lsh[t] = aloop[t];
    __syncthreads();
    int i = blockIdx.x * 256 + t;
    if (i >= N_ETOT) return;
    int e = csr[i].y;
    float a[LAYERS][4];
    if (e < N_EDGES) {
        float er[12];
        const float* ep = ea + (size_t)e * ED;
#pragma unroll
        for (int d = 0; d < 12; d++) er[d] = ep[d];
#pragma unroll
        for (int l = 0; l < LAYERS; l++)
#pragma unroll
            for (int h = 0; h < 4; h++) {
                float s = 0.f;
#pragma unroll
                for (int d = 0; d < 12; d++) s += er[d] * wsh[l * 48 + d * 4 + h];
                a[l][h] = s;
            }
    } else {
#pragma unroll
        for (int l = 0; l < LAYERS; l++)
#pragma unroll
            for (int h = 0; h < 4; h++) a[l][h] = lsh[l * 4 + h];
    }
#pragma unroll
    for (int l = 0; l < LAYERS; l++)
        aecsr[(size_t)l * N_ETOT + i] =
            make_uint2(bf16pair(a[l][0], a[l][1]), bf16pair(a[l][2], a[l][3]));
}

// ---------------------------------------------------------------------------
// Fused BN-update + MFMA projection (layers 1..3).
// ---------------------------------------------------------------------------
template <int ADD>
__launch_bounds__(256)
__global__ void gemm_fused_kernel(const float* __restrict__ outb,
                                  const float* __restrict__ bnsum,
                                  const float* __restrict__ bnsum2,
                                  const float* __restrict__ gamma,
                                  const float* __restrict__ beta,
                                  float* __restrict__ hA,
                                  const unsigned short* __restrict__ wb,
                                  const float* __restrict__ att_s,
                                  const float* __restrict__ att_d,
                                  unsigned* __restrict__ xpb,
                                  float* __restrict__ asrc, float* __restrict__ adst) {
    __shared__ float lds[4][16][129];
    __shared__ float sc_s[128], sh_s[128];
    int t = threadIdx.x;
    if (t < 128) {
        float mu = bnsum[t] / (float)N_NODES;
        float var = bnsum2[t] / (float)N_NODES - mu * mu;
        float inv = rsqrtf(var + BN_EPS);
        float g = gamma[t] * inv;
        sc_s[t] = g;
        sh_s[t] = beta[t] - mu * g;
    }
    __syncthreads();

    int w = t >> 6, lane = t & 63;
    int rbase = blockIdx.x * 64 + w * 16;
    int mrow = lane & 15, quad = lane >> 4;
    int arow = rbase + mrow;
    bool owner = arow < N_NODES;
    int ar = min(arow, N_NODES - 1);

    floatx4 acc[8];
#pragma unroll
    for (int nt = 0; nt < 8; nt++) acc[nt] = (floatx4){0.f, 0.f, 0.f, 0.f};

    const short8* wb8 = (const short8*)wb;
#pragma unroll
    for (int kt = 0; kt < 4; kt++) {
        int cb = kt * 32 + quad * 8;
        const float4* ob = (const float4*)(outb + (size_t)ar * 128 + cb);
        float4 o0 = ob[0], o1 = ob[1];
        float v[8];
        v[0] = fmaxf(o0.x * sc_s[cb + 0] + sh_s[cb + 0], 0.f);
        v[1] = fmaxf(o0.y * sc_s[cb + 1] + sh_s[cb + 1], 0.f);
        v[2] = fmaxf(o0.z * sc_s[cb + 2] + sh_s[cb + 2], 0.f);
        v[3] = fmaxf(o0.w * sc_s[cb + 3] + sh_s[cb + 3], 0.f);
        v[4] = fmaxf(o1.x * sc_s[cb + 4] + sh_s[cb + 4], 0.f);
        v[5] = fmaxf(o1.y * sc_s[cb + 5] + sh_s[cb + 5], 0.f);
        v[6] = fmaxf(o1.z * sc_s[cb + 6] + sh_s[cb + 6], 0.f);
        v[7] = fmaxf(o1.w * sc_s[cb + 7] + sh_s[cb + 7], 0.f);
        if (ADD) {
            const float4* hp = (const float4*)(hA + (size_t)ar * 128 + cb);
            float4 h0 = hp[0], h1 = hp[1];
            v[0] += h0.x; v[1] += h0.y; v[2] += h0.z; v[3] += h0.w;
            v[4] += h1.x; v[5] += h1.y; v[6] += h1.z; v[7] += h1.w;
        }
        if (owner) {
            float4* hw = (float4*)(hA + (size_t)ar * 128 + cb);
            hw[0] = make_float4(v[0], v[1], v[2], v[3]);
            hw[1] = make_float4(v[4], v[5], v[6], v[7]);
        }
        uint4 pk;
        pk.x = bf16pair(v[0], v[1]); pk.y = bf16pair(v[2], v[3]);
        pk.z = bf16pair(v[4], v[5]); pk.w = bf16pair(v[6], v[7]);
        short8 afrag = *(short8*)&pk;
#pragma unroll
        for (int nt = 0; nt < 8; nt++) {
            short8 bfrag = wb8[(kt * 8 + nt) * 64 + lane];
            acc[nt] = __builtin_amdgcn_mfma_f32_16x16x32_bf16(afrag, bfrag, acc[nt], 0, 0, 0);
        }
    }

#pragma unroll
    for (int nt = 0; nt < 8; nt++)
#pragma unroll
        for (int rr = 0; rr < 4; rr++)
            lds[w][quad * 4 + rr][nt * 16 + mrow] = acc[nt][rr];

    int row = lane >> 2, h = lane & 3;
    int r = rbase + row;
    float vals[32];
    float ps = 0.f, pd = 0.f;
#pragma unroll
    for (int c = 0; c < 32; c++) {
        float v = lds[w][row][h * 32 + c];
        vals[c] = v;
        ps += v * att_s[h * 32 + c];
        pd += v * att_d[h * 32 + c];
    }
    if (r < N_NODES) {
        unsigned* dstp = xpb + (size_t)r * 64 + h * 16;
#pragma unroll
        for (int qq = 0; qq < 4; qq++) {
            uint4 o;
            o.x = bf16pair(vals[qq * 8 + 0], vals[qq * 8 + 1]);
            o.y = bf16pair(vals[qq * 8 + 2], vals[qq * 8 + 3]);
            o.z = bf16pair(vals[qq * 8 + 4], vals[qq * 8 + 5]);
            o.w = bf16pair(vals[qq * 8 + 6], vals[qq * 8 + 7]);
            ((uint4*)dstp)[qq] = o;
        }
        asrc[r * 4 + h] = ps;
        adst[r * 4 + h] = pd;
    }
}

// ---------------------------------------------------------------------------
// Single-pass aggregation with on-the-fly softmax weights.
// ---------------------------------------------------------------------------
__launch_bounds__(256)
__global__ void node_kernel(const uint2* __restrict__ aecsr, const float* __restrict__ asrc,
                            const float* __restrict__ adst, const int* __restrict__ rowpR,
                            const int2* __restrict__ csr, const unsigned* __restrict__ xpb,
                            float* __restrict__ out) {
    int gw = (blockIdx.x * blockDim.x + threadIdx.x) >> 6;
    int lane = threadIdx.x & 63;
    if (gw >= N_NODES) return;
    int sub = lane >> 4;
    int sl  = lane & 15;
    int h   = sl >> 2;
    int beg = rowpR[gw * R_REP], end = rowpR[(gw + 1) * R_REP];
    const uint4* xp4 = (const uint4*)xpb;
    float adh = adst[gw * 4 + h];

    float a[8];
#pragma unroll
    for (int c = 0; c < 8; c++) a[c] = 0.f;
    float den = 0.f;

#define PROC(JJ)                                                                 \
    {                                                                            \
        int2 se = csr[JJ];                                                       \
        uint2 ae = aecsr[JJ];                                                    \
        unsigned aw = (h & 2) ? ae.y : ae.x;                                     \
        float aeh = __uint_as_float((h & 1) ? (aw & 0xFFFF0000u) : (aw << 16));  \
        float ash = asrc[se.x * 4 + h];                                          \
        uint4 v = xp4[(size_t)se.x * 16 + sl];                                   \
        float lg = ash + adh + aeh;                                              \
        lg = (lg > 0.f) ? lg : 0.2f * lg;                                        \
        float ex = __expf(fminf(lg, 60.f));                                      \
        a[0] += ex * __uint_as_float(v.x << 16);                                 \
        a[1] += ex * __uint_as_float(v.x & 0xFFFF0000u);                         \
        a[2] += ex * __uint_as_float(v.y << 16);                                 \
        a[3] += ex * __uint_as_float(v.y & 0xFFFF0000u);                         \
        a[4] += ex * __uint_as_float(v.z << 16);                                 \
        a[5] += ex * __uint_as_float(v.z & 0xFFFF0000u);                         \
        a[6] += ex * __uint_as_float(v.w << 16);                                 \
        a[7] += ex * __uint_as_float(v.w & 0xFFFF0000u);                         \
        den += ex;                                                               \
    }

    int j = beg + sub;
    for (; j + 12 < end; j += 16) {
        PROC(j); PROC(j + 4); PROC(j + 8); PROC(j + 12);
    }
    for (; j < end; j += 4) PROC(j);
#undef PROC

#pragma unroll
    for (int c = 0; c < 8; c++) {
        a[c] += __shfl_xor(a[c], 16);
        a[c] += __shfl_xor(a[c], 32);
    }
    den += __shfl_xor(den, 16);
    den += __shfl_xor(den, 32);
    float inv = 1.0f / den;
    if (sub == 0) {
        float* op = out + (size_t)gw * 128 + sl * 8;
        ((float4*)op)[0] = make_float4(a[0] * inv, a[1] * inv, a[2] * inv, a[3] * inv);
        ((float4*)op)[1] = make_float4(a[4] * inv, a[5] * inv, a[6] * inv, a[7] * inv);
    }
}

// ---------------------------------------------------------------------------
// BatchNorm statistics; final-layer standalone update (writes outp).
// ---------------------------------------------------------------------------
__launch_bounds__(256)
__global__ void bnstats_kernel(const float* __restrict__ h, float* __restrict__ bnsum,
                               float* __restrict__ bnsum2) {
    __shared__ float ls[256], ls2[256];
    int t = threadIdx.x;
    int c = t & 127, half = t >> 7;
    int r0 = blockIdx.x * 128;
    float s = 0.f, s2 = 0.f;
    int rend = min(r0 + 128, N_NODES);
    for (int r = r0 + half; r < rend; r += 2) {
        float v = h[(size_t)r * 128 + c];
        s += v; s2 += v * v;
    }
    ls[t] = s; ls2[t] = s2;
    __syncthreads();
    if (half == 0) {
        s += ls[t + 128]; s2 += ls2[t + 128];
        atomicAdd(&bnsum[c], s);
        atomicAdd(&bnsum2[c], s2);
    }
}

__launch_bounds__(256)
__global__ void finalupd_kernel(const float* __restrict__ outb, const float* __restrict__ bnsum,
                                const float* __restrict__ bnsum2, const float* __restrict__ gamma,
                                const float* __restrict__ beta, const float* __restrict__ hA,
                                float* __restrict__ dst) {
    __shared__ float sc_s[128], sh_s[128];
    int t = threadIdx.x;
    if (t < 128) {
        float mu = bnsum[t] / (float)N_NODES;
        float var = bnsum2[t] / (float)N_NODES - mu * mu;
        float inv = rsqrtf(var + BN_EPS);
        float g = gamma[t] * inv;
        sc_s[t] = g;
        sh_s[t] = beta[t] - mu * g;
    }
    __syncthreads();
    int i = blockIdx.x * blockDim.x + t;
    if (i >= N_NODES * 32) return;
    int c4 = (i & 31) * 4;
    float4 o = ((const float4*)outb)[i];
    float4 hh = ((const float4*)hA)[i];
    float4 v;
    v.x = fmaxf(o.x * sc_s[c4 + 0] + sh_s[c4 + 0], 0.f) + hh.x;
    v.y = fmaxf(o.y * sc_s[c4 + 1] + sh_s[c4 + 1], 0.f) + hh.y;
    v.z = fmaxf(o.z * sc_s[c4 + 2] + sh_s[c4 + 2], 0.f) + hh.z;
    v.w = fmaxf(o.w * sc_s[c4 + 3] + sh_s[c4 + 3], 0.f) + hh.w;
    ((float4*)dst)[i] = v;
}

// ---------------------------------------------------------------------------
extern "C" void kernel_launch(void* const* d_in, const int* in_sizes, int n_in,
                              void* d_out, int out_size, void* d_ws, size_t ws_size,
                              hipStream_t stream) {
    const float* x          = (const float*)d_in[0];
    const int*   edge_index = (const int*)d_in[1];
    const float* edge_attr  = (const float*)d_in[2];
    const float* Wp         = (const float*)d_in[3];
    const float* bp         = (const float*)d_in[4];
    const float* W          = (const float*)d_in[5];
    const float* We         = (const float*)d_in[6];
    const float* att_src    = (const float*)d_in[7];
    const float* att_dst    = (const float*)d_in[8];
    const float* att_edge   = (const float*)d_in[9];
    // d_in[10] bias: absorbed exactly by training-mode BN -> skipped
    const float* gamma      = (const float*)d_in[11];
    const float* beta       = (const float*)d_in[12];
    float* outp = (float*)d_out;

    const int* ei_src = edge_index;
    const int* ei_dst = edge_index + N_EDGES;

    char* p = (char*)d_ws;
    auto alloc = [&](size_t nbytes) {
        char* r = p;
        p += (nbytes + 255) & ~(size_t)255;
        return r;
    };
    // zero-initialized region: hist2 | easum | bnsum(4 layers x 256)
    int*   hist2    = (int*)alloc((size_t)RN * 4);
    float* easum    = (float*)alloc(16 * 4);
    float* bnsumall = (float*)alloc((size_t)LAYERS * 256 * 4);
    size_t zero_bytes = (char*)(bnsumall + LAYERS * 256) - (char*)hist2;

    float* hA       = (float*)alloc((size_t)N_NODES * 128 * 4);
    unsigned* hAb   = (unsigned*)alloc((size_t)N_NODES * 64 * 4);   // bf16x2 (layer-0 A feed)
    unsigned* xpb   = (unsigned*)alloc((size_t)N_NODES * 64 * 4);   // bf16x2 gather payload
    float* outb     = (float*)alloc((size_t)N_NODES * 128 * 4);
    float* asrc     = (float*)alloc((size_t)N_NODES * 4 * 4);
    float* adst     = (float*)alloc((size_t)N_NODES * 4 * 4);
    float* wea_all  = (float*)alloc((LAYERS * 48 + 16) * 4);
    float* aloop    = wea_all + LAYERS * 48;
    unsigned short* wb = (unsigned short*)alloc((size_t)LAYERS * 16384 * 2);
    int* rowpR      = (int*)alloc(((size_t)RN + 1) * 4);
    int* rankbuf    = (int*)alloc((size_t)N_ETOT * 4);
    int2* csr       = (int2*)alloc((size_t)N_ETOT * 8);
    uint2* aecsr    = (uint2*)alloc((size_t)LAYERS * N_ETOT * 8);
    int* bsum       = (int*)alloc(1024 * 4);
    int* boff       = (int*)alloc(1024 * 4);

    (void)hipMemsetAsync(hist2, 0, zero_bytes, stream);

    // ---- preamble: CSR build + folded matrices + W pack + gemm0, overlapped ----
    pre1_kernel<<<GB + EB + 256 + WB, 256, 0, stream>>>(
        ei_dst, hist2, rankbuf, edge_attr, easum, W, wb, x, Wp, bp, hA, hAb);
    blocksum_kernel<<<SB2, 256, 0, stream>>>(hist2, bsum);
    pre2_kernel<<<2, 256, 0, stream>>>(bsum, boff, rowpR, easum, We, att_edge, wea_all, aloop);
    rowp_kernel<<<SB2, 256, 0, stream>>>(hist2, boff, rowpR);
    pre3_kernel<<<GB + EB, 256, 0, stream>>>(
        (const unsigned short*)hAb, wb, att_src, att_dst, xpb, asrc, adst,
        ei_src, ei_dst, rankbuf, rowpR, csr);
    pre4_kernel<<<EB, 256, 0, stream>>>(csr, edge_attr, wea_all, aloop, aecsr);

    for (int l = 0; l < LAYERS; l++) {
        float* bnsum  = bnsumall + l * 256;
        float* bnsum2 = bnsum + 128;
        node_kernel<<<(N_NODES + 3) / 4, 256, 0, stream>>>(
            aecsr + (size_t)l * N_ETOT, asrc, adst, rowpR, csr, xpb, outb);
        bnstats_kernel<<<(N_NODES + 127) / 128, 256, 0, stream>>>(outb, bnsum, bnsum2);
        if (l < LAYERS - 1) {
            // fused: h_{l+1} = relu(bn_l(outb)) (+ hA if l>0) -> hA, A-frag in-reg
            if (l == 0)
                gemm_fused_kernel<0><<<GB, 256, 0, stream>>>(
                    outb, bnsum, bnsum2, gamma + l * 128, beta + l * 128, hA,
                    wb + (size_t)(l + 1) * 16384, att_src + (l + 1) * 128,
                    att_dst + (l + 1) * 128, xpb, asrc, adst);
            else
                gemm_fused_kernel<1><<<GB, 256, 0, stream>>>(
                    outb, bnsum, bnsum2, gamma + l * 128, beta + l * 128, hA,
                    wb + (size_t)(l + 1) * 16384, att_src + (l + 1) * 128,
                    att_dst + (l + 1) * 128, xpb, asrc, adst);
        } else {
            finalupd_kernel<<<(N_NODES * 32 + 255) / 256, 256, 0, stream>>>(
                outb, bnsum, bnsum2, gamma + l * 128, beta + l * 128, hA, outp);
        }
    }
}

// Round 3
// 569.466 us; speedup vs baseline: 1.1124x; 1.0492x over previous
//
#include <hip/hip_runtime.h>

// Problem constants (match reference setup_inputs)
constexpr int N_NODES = 50000;
constexpr int N_EDGES = 800000;
constexpr int N_ETOT  = N_EDGES + N_NODES;   // with self loops
constexpr int HID     = 128;
constexpr int HEADS   = 4;
constexpr int ED      = 12;
constexpr int LAYERS  = 4;
constexpr float BN_EPS = 1e-5f;
constexpr int EB = (N_ETOT + 255) / 256;          // 3321 edge blocks
constexpr int GB = (N_NODES + 63) / 64;           // 782 gemm blocks
constexpr int WB = (LAYERS * HID * HID + 255) / 256;  // 256 packW blocks
// counting-sort CSR build (all-LDS atomics)
constexpr int CHUNK  = 2048;                          // edges per count/scatter block
constexpr int NCHUNK = (N_ETOT + CHUNK - 1) / CHUNK;  // 416
constexpr int NB     = (N_NODES + 127) / 128;         // 391 coarse buckets (dst>>7)
constexpr int F_TOT  = NB * NCHUNK;                   // 162656 flattened (bucket,chunk)
constexpr int SB3    = (F_TOT + 255) / 256;           // 636 scan blocks

typedef __attribute__((ext_vector_type(8))) short short8;
typedef __attribute__((ext_vector_type(4))) float floatx4;

__device__ inline unsigned bf16pair(float a, float b) {
    unsigned ua = __float_as_uint(a), ub = __float_as_uint(b);
    ua = (ua + 0x7FFFu + ((ua >> 16) & 1u)) >> 16;
    ub = (ub + 0x7FFFu + ((ub >> 16) & 1u)) >> 16;
    return ua | (ub << 16);
}

// ---------------------------------------------------------------------------
// pre1: [gemm0 | countA | eamean | packW] — all independent. countA: per-chunk
// LDS histogram over NB coarse buckets (dst>>7); coalesced counts write.
// No fabric atomics anywhere.
// ---------------------------------------------------------------------------
__launch_bounds__(256)
__global__ void pre1_kernel(const int* __restrict__ dst, int* __restrict__ counts,
                            const float* __restrict__ ea, float* __restrict__ easum,
                            const float* __restrict__ W, unsigned short* __restrict__ wb,
                            const float* __restrict__ A, const float* __restrict__ B,
                            const float* __restrict__ bias, float* __restrict__ C,
                            unsigned* __restrict__ Cb) {
    __shared__ float smem[64 * 128];   // gemm0 Bs; countA uses NB ints; eamean 12 floats
    int bid = blockIdx.x, t = threadIdx.x;
    if (bid < GB) {
        // ---- gemm0: h = relu(x @ Wp + bp), dual f32/bf16 out ----
        constexpr int K = 64;
        const float4* B4 = (const float4*)B;
        float4* Bs4 = (float4*)smem;
#pragma unroll
        for (int i = t; i < K * 32; i += 256) Bs4[i] = B4[i];
        __syncthreads();

        int c0 = (t & 15) * 8;
        int r0 = (t >> 4) * 4;
        int rbase = bid * 64 + r0;

        float acc[4][8];
#pragma unroll
        for (int j = 0; j < 4; j++)
#pragma unroll
            for (int c = 0; c < 8; c++) acc[j][c] = 0.f;

        const float4* A4 = (const float4*)A;
        int rg[4];
#pragma unroll
        for (int j = 0; j < 4; j++) rg[j] = min(rbase + j, N_NODES - 1);

        for (int kk = 0; kk < K; kk += 4) {
            float4 av[4];
#pragma unroll
            for (int j = 0; j < 4; j++) av[j] = A4[(size_t)rg[j] * (K / 4) + (kk >> 2)];
            float a_arr[4][4];
#pragma unroll
            for (int j = 0; j < 4; j++) {
                a_arr[j][0] = av[j].x; a_arr[j][1] = av[j].y;
                a_arr[j][2] = av[j].z; a_arr[j][3] = av[j].w;
            }
#pragma unroll
            for (int jj = 0; jj < 4; jj++) {
                float4 b0 = Bs4[(kk + jj) * 32 + (c0 >> 2)];
                float4 b1 = Bs4[(kk + jj) * 32 + (c0 >> 2) + 1];
#pragma unroll
                for (int j = 0; j < 4; j++) {
                    float a = a_arr[j][jj];
                    acc[j][0] += a * b0.x; acc[j][1] += a * b0.y;
                    acc[j][2] += a * b0.z; acc[j][3] += a * b0.w;
                    acc[j][4] += a * b1.x; acc[j][5] += a * b1.y;
                    acc[j][6] += a * b1.z; acc[j][7] += a * b1.w;
                }
            }
        }

#pragma unroll
        for (int j = 0; j < 4; j++) {
            int r = rbase + j;
            if (r < N_NODES) {
                float o[8];
#pragma unroll
                for (int c = 0; c < 8; c++) o[c] = fmaxf(acc[j][c] + bias[c0 + c], 0.f);
                ((float4*)(C + (size_t)r * 128 + c0))[0] = make_float4(o[0], o[1], o[2], o[3]);
                ((float4*)(C + (size_t)r * 128 + c0 + 4))[0] = make_float4(o[4], o[5], o[6], o[7]);
                uint4 pk;
                pk.x = bf16pair(o[0], o[1]); pk.y = bf16pair(o[2], o[3]);
                pk.z = bf16pair(o[4], o[5]); pk.w = bf16pair(o[6], o[7]);
                ((uint4*)(Cb + (size_t)r * 64 + (c0 >> 1)))[0] = pk;
            }
        }
    } else if (bid < GB + NCHUNK) {
        // ---- countA: LDS histogram of coarse bucket (dst>>7) for one chunk ----
        int chunk = bid - GB;
        int* lh = (int*)smem;
        for (int i = t; i < NB; i += 256) lh[i] = 0;
        __syncthreads();
        int e0 = chunk * CHUNK;
        int eend = min(e0 + CHUNK, N_ETOT);
        for (int e = e0 + t; e < eend; e += 256) {
            int d = (e < N_EDGES) ? dst[e] : (e - N_EDGES);
            atomicAdd(&lh[d >> 7], 1);
        }
        __syncthreads();
        for (int i = t; i < NB; i += 256) counts[(size_t)chunk * NB + i] = lh[i];
    } else if (bid < GB + NCHUNK + 256) {
        int b2 = bid - GB - NCHUNK;
        float* ls = smem;
        if (t < 12) ls[t] = 0.f;
        __syncthreads();
        float loc[12];
#pragma unroll
        for (int d = 0; d < 12; d++) loc[d] = 0.f;
        for (int e = b2 * 256 + t; e < N_EDGES; e += 256 * 256) {
            const float* er = ea + (size_t)e * ED;
#pragma unroll
            for (int d = 0; d < 12; d++) loc[d] += er[d];
        }
#pragma unroll
        for (int d = 0; d < 12; d++) atomicAdd(&ls[d], loc[d]);
        __syncthreads();
        if (t < 12) atomicAdd(&easum[t], ls[t]);
    } else {
        int idx = (bid - GB - NCHUNK - 256) * 256 + t;
        if (idx < LAYERS * HID * HID) {
            int l = idx >> 14;
            int k = (idx >> 7) & 127;
            int n = idx & 127;
            unsigned u = __float_as_uint(W[idx]);
            u = (u + 0x7FFFu + ((u >> 16) & 1u)) >> 16;
            int kt = k >> 5, q = (k & 31) >> 3, j = k & 7;
            int nt = n >> 4, c = n & 15;
            int lane = q * 16 + c;
            wb[(size_t)l * 16384 + ((size_t)(kt * 8 + nt) * 64 + lane) * 8 + j] =
                (unsigned short)u;
        }
    }
}

// blocksum over flattened (bucket-major) count matrix: j = b*NCHUNK + c,
// stored as counts[c*NB + b].
__global__ void blocksum2_kernel(const int* __restrict__ counts, int* __restrict__ bsum) {
    __shared__ int sd[256];
    int t = threadIdx.x;
    int j = blockIdx.x * 256 + t;
    int v = 0;
    if (j < F_TOT) {
        int bb = j / NCHUNK, cc = j - bb * NCHUNK;
        v = counts[(size_t)cc * NB + bb];
    }
    sd[t] = v;
    __syncthreads();
#pragma unroll
    for (int off = 128; off; off >>= 1) {
        if (t < off) sd[t] += sd[t + off];
        __syncthreads();
    }
    if (t == 0) bsum[blockIdx.x] = sd[0];
}

// ---------------------------------------------------------------------------
// pre2: [bscan | prep] — block 0 scans SB3=636 block sums (3/thread) and
// writes sentinels; block 1 folds We/att_edge.
// ---------------------------------------------------------------------------
__launch_bounds__(256)
__global__ void pre2_kernel(const int* __restrict__ bsum, int* __restrict__ boff,
                            int* __restrict__ chunkbase, int* __restrict__ rowp,
                            const float* __restrict__ easum,
                            const float* __restrict__ We, const float* __restrict__ att_edge,
                            float* __restrict__ wea_all, float* __restrict__ aloop) {
    int t = threadIdx.x;
    if (blockIdx.x == 0) {
        __shared__ int sd[256];
        int b = 3 * t;
        int v0 = (b + 0 < SB3) ? bsum[b + 0] : 0;
        int v1 = (b + 1 < SB3) ? bsum[b + 1] : 0;
        int v2 = (b + 2 < SB3) ? bsum[b + 2] : 0;
        int tot = v0 + v1 + v2;
        sd[t] = tot;
        __syncthreads();
#pragma unroll
        for (int off = 1; off < 256; off <<= 1) {
            int u = (t >= off) ? sd[t - off] : 0;
            __syncthreads();
            sd[t] += u;
            __syncthreads();
        }
        int excl = sd[t] - tot;
        if (b + 0 < SB3) boff[b + 0] = excl;
        if (b + 1 < SB3) boff[b + 1] = excl + v0;
        if (b + 2 < SB3) boff[b + 2] = excl + v0 + v1;
        if (t == 255) {
            chunkbase[F_TOT] = sd[255];    // == N_ETOT
            rowp[N_NODES] = N_ETOT;
        }
    } else {
        __shared__ float em[12];
        __shared__ float weash[LAYERS * ED * HEADS];
        if (t < 12) em[t] = easum[t] / (float)N_EDGES;
        if (t < LAYERS * ED * HEADS) {
            int l = t / (ED * HEADS);
            int r = t % (ED * HEADS);
            int d = r / HEADS;
            int h = r % HEADS;
            float sum = 0.f;
#pragma unroll
            for (int c = 0; c < 32; c++)
                sum += We[((size_t)(l * ED + d)) * HID + h * 32 + c] *
                       att_edge[(l * HEADS + h) * 32 + c];
            wea_all[t] = sum;
            weash[t] = sum;
        }
        __syncthreads();
        if (t < LAYERS * HEADS) {
            int l = t / HEADS, h = t % HEADS;
            float s = 0.f;
#pragma unroll
            for (int d = 0; d < 12; d++) s += em[d] * weash[l * ED * HEADS + d * HEADS + h];
            aloop[t] = s;
        }
    }
}

// add-back: chunkbase[j] = exclusive scan of translated counts
__global__ void addback_kernel(const int* __restrict__ counts, const int* __restrict__ boff,
                               int* __restrict__ chunkbase) {
    __shared__ int sd[256];
    int t = threadIdx.x;
    int j = blockIdx.x * 256 + t;
    int v = 0;
    if (j < F_TOT) {
        int bb = j / NCHUNK, cc = j - bb * NCHUNK;
        v = counts[(size_t)cc * NB + bb];
    }
    sd[t] = v;
    __syncthreads();
#pragma unroll
    for (int off = 1; off < 256; off <<= 1) {
        int u = (t >= off) ? sd[t - off] : 0;
        __syncthreads();
        sd[t] += u;
        __syncthreads();
    }
    if (j < F_TOT) chunkbase[j] = sd[t] - v + boff[blockIdx.x];
}

// ---------------------------------------------------------------------------
// pre3: [xp-proj MFMA (layer 0) | scatterC]. scatterC: LDS-ranked partition
// into coarse-bucket regions; writes are ~NB short contiguous streams/block.
// ---------------------------------------------------------------------------
__launch_bounds__(256)
__global__ void pre3_kernel(const unsigned short* __restrict__ hAb,
                            const unsigned short* __restrict__ wb,
                            const float* __restrict__ att_s, const float* __restrict__ att_d,
                            unsigned* __restrict__ xpb,
                            float* __restrict__ asrc, float* __restrict__ adst,
                            const int* __restrict__ src, const int* __restrict__ dst,
                            const int* __restrict__ chunkbase, int2* __restrict__ bucketed) {
    __shared__ float smem[4 * 16 * 129];   // 33 KB
    int t = threadIdx.x;
    if (blockIdx.x >= GB) {
        int chunk = blockIdx.x - GB;
        int* lb = (int*)smem;       // NB bases
        int* lh = lb + NB;          // NB cursors
        for (int i = t; i < NB; i += 256) {
            lb[i] = chunkbase[(size_t)i * NCHUNK + chunk];
            lh[i] = 0;
        }
        __syncthreads();
        int e0 = chunk * CHUNK;
        int eend = min(e0 + CHUNK, N_ETOT);
        for (int e = e0 + t; e < eend; e += 256) {
            int s, d;
            if (e < N_EDGES) { s = src[e]; d = dst[e]; }
            else             { s = d = e - N_EDGES; }
            int b = d >> 7;
            int lr = atomicAdd(&lh[b], 1);
            bucketed[lb[b] + lr] = make_int2(s, e | ((d & 127) << 20));
        }
        return;
    }
    // ---- plain MFMA projection (layer 0), A from hAb ----
    int bid = blockIdx.x;
    float (*lds)[16][129] = (float (*)[16][129])smem;
    int w = t >> 6, lane = t & 63;
    int rbase = bid * 64 + w * 16;
    int mrow = lane & 15, quad = lane >> 4;

    floatx4 acc[8];
#pragma unroll
    for (int nt = 0; nt < 8; nt++) acc[nt] = (floatx4){0.f, 0.f, 0.f, 0.f};

    int arow = min(rbase + mrow, N_NODES - 1);
    const short8* wb8 = (const short8*)wb;
#pragma unroll
    for (int kt = 0; kt < 4; kt++) {
        short8 afrag = *(const short8*)(hAb + (size_t)arow * 128 + kt * 32 + quad * 8);
#pragma unroll
        for (int nt = 0; nt < 8; nt++) {
            short8 bfrag = wb8[(kt * 8 + nt) * 64 + lane];
            acc[nt] = __builtin_amdgcn_mfma_f32_16x16x32_bf16(afrag, bfrag, acc[nt], 0, 0, 0);
        }
    }
#pragma unroll
    for (int nt = 0; nt < 8; nt++)
#pragma unroll
        for (int rr = 0; rr < 4; rr++)
            lds[w][quad * 4 + rr][nt * 16 + mrow] = acc[nt][rr];

    int row = lane >> 2, h = lane & 3;
    int r = rbase + row;
    float vals[32];
    float ps = 0.f, pd = 0.f;
#pragma unroll
    for (int c = 0; c < 32; c++) {
        float v = lds[w][row][h * 32 + c];
        vals[c] = v;
        ps += v * att_s[h * 32 + c];
        pd += v * att_d[h * 32 + c];
    }
    if (r < N_NODES) {
        unsigned* dstp = xpb + (size_t)r * 64 + h * 16;
#pragma unroll
        for (int qq = 0; qq < 4; qq++) {
            uint4 o;
            o.x = bf16pair(vals[qq * 8 + 0], vals[qq * 8 + 1]);
            o.y = bf16pair(vals[qq * 8 + 2], vals[qq * 8 + 3]);
            o.z = bf16pair(vals[qq * 8 + 4], vals[qq * 8 + 5]);
            o.w = bf16pair(vals[qq * 8 + 6], vals[qq * 8 + 7]);
            ((uint4*)dstp)[qq] = o;
        }
        asrc[r * 4 + h] = ps;
        adst[r * 4 + h] = pd;
    }
}

// ---------------------------------------------------------------------------
// csrd: per-bucket CSR finalize. 128-bin LDS histogram + scan -> rowp; scatter
// bucket edges into final csr (contiguous 17KB window, L2-local).
// ---------------------------------------------------------------------------
__launch_bounds__(256)
__global__ void csrd_kernel(const int2* __restrict__ bucketed, const int* __restrict__ chunkbase,
                            int2* __restrict__ csr, int* __restrict__ rowp) {
    __shared__ int hist[128], exc[128], cur[128];
    int b = blockIdx.x, t = threadIdx.x;
    int base = chunkbase[(size_t)b * NCHUNK];
    int cend = chunkbase[(size_t)(b + 1) * NCHUNK];
    int cnt = cend - base;
    if (t < 128) { hist[t] = 0; cur[t] = 0; }
    __syncthreads();
    for (int i = t; i < cnt; i += 256)
        atomicAdd(&hist[(bucketed[base + i].y >> 20) & 127], 1);
    __syncthreads();
    if (t < 128) exc[t] = hist[t];
    __syncthreads();
#pragma unroll
    for (int off = 1; off < 128; off <<= 1) {
        int u = (t < 128 && t >= off) ? exc[t - off] : 0;
        __syncthreads();
        if (t < 128) exc[t] += u;
        __syncthreads();
    }
    if (t < 128) {
        exc[t] -= hist[t];   // exclusive
        int node = b * 128 + t;
        if (node < N_NODES) rowp[node] = base + exc[t];
    }
    __syncthreads();
    for (int i = t; i < cnt; i += 256) {
        int2 r = bucketed[base + i];
        int dl = (r.y >> 20) & 127;
        int lr = atomicAdd(&cur[dl], 1);
        csr[base + exc[dl] + lr] = make_int2(r.x, r.y & 0xFFFFF);
    }
}

// ---------------------------------------------------------------------------
// pre4: aedgep — per-edge attention terms for all layers in CSR order (bf16x4).
// ---------------------------------------------------------------------------
__launch_bounds__(256)
__global__ void pre4_kernel(const int2* __restrict__ csr, const float* __restrict__ ea,
                            const float* __restrict__ wea_all, const float* __restrict__ aloop,
                            uint2* __restrict__ aecsr) {
    __shared__ float wsh[LAYERS * ED * HEADS];
    __shared__ float lsh[LAYERS * HEADS];
    int t = threadIdx.x;
    if (t < LAYERS * ED * HEADS) wsh[t] = wea_all[t];
    if (t < LAYERS * HEADS) lsh[t] = aloop[t];
    __syncthreads();
    int i = blockIdx.x * 256 + t;
    if (i >= N_ETOT) return;
    int e = csr[i].y;
    float a[LAYERS][4];
    if (e < N_EDGES) {
        float er[12];
        const float* ep = ea + (size_t)e * ED;
#pragma unroll
        for (int d = 0; d < 12; d++) er[d] = ep[d];
#pragma unroll
        for (int l = 0; l < LAYERS; l++)
#pragma unroll
            for (int h = 0; h < 4; h++) {
                float s = 0.f;
#pragma unroll
                for (int d = 0; d < 12; d++) s += er[d] * wsh[l * 48 + d * 4 + h];
                a[l][h] = s;
            }
    } else {
#pragma unroll
        for (int l = 0; l < LAYERS; l++)
#pragma unroll
            for (int h = 0; h < 4; h++) a[l][h] = lsh[l * 4 + h];
    }
#pragma unroll
    for (int l = 0; l < LAYERS; l++)
        aecsr[(size_t)l * N_ETOT + i] =
            make_uint2(bf16pair(a[l][0], a[l][1]), bf16pair(a[l][2], a[l][3]));
}

// ---------------------------------------------------------------------------
// Fused BN-update + MFMA projection (layers 1..3).
// ---------------------------------------------------------------------------
template <int ADD>
__launch_bounds__(256)
__global__ void gemm_fused_kernel(const float* __restrict__ outb,
                                  const float* __restrict__ bnsum,
                                  const float* __restrict__ bnsum2,
                                  const float* __restrict__ gamma,
                                  const float* __restrict__ beta,
                                  float* __restrict__ hA,
                                  const unsigned short* __restrict__ wb,
                                  const float* __restrict__ att_s,
                                  const float* __restrict__ att_d,
                                  unsigned* __restrict__ xpb,
                                  float* __restrict__ asrc, float* __restrict__ adst) {
    __shared__ float lds[4][16][129];
    __shared__ float sc_s[128], sh_s[128];
    int t = threadIdx.x;
    if (t < 128) {
        float mu = bnsum[t] / (float)N_NODES;
        float var = bnsum2[t] / (float)N_NODES - mu * mu;
        float inv = rsqrtf(var + BN_EPS);
        float g = gamma[t] * inv;
        sc_s[t] = g;
        sh_s[t] = beta[t] - mu * g;
    }
    __syncthreads();

    int w = t >> 6, lane = t & 63;
    int rbase = blockIdx.x * 64 + w * 16;
    int mrow = lane & 15, quad = lane >> 4;
    int arow = rbase + mrow;
    bool owner = arow < N_NODES;
    int ar = min(arow, N_NODES - 1);

    floatx4 acc[8];
#pragma unroll
    for (int nt = 0; nt < 8; nt++) acc[nt] = (floatx4){0.f, 0.f, 0.f, 0.f};

    const short8* wb8 = (const short8*)wb;
#pragma unroll
    for (int kt = 0; kt < 4; kt++) {
        int cb = kt * 32 + quad * 8;
        const float4* ob = (const float4*)(outb + (size_t)ar * 128 + cb);
        float4 o0 = ob[0], o1 = ob[1];
        float v[8];
        v[0] = fmaxf(o0.x * sc_s[cb + 0] + sh_s[cb + 0], 0.f);
        v[1] = fmaxf(o0.y * sc_s[cb + 1] + sh_s[cb + 1], 0.f);
        v[2] = fmaxf(o0.z * sc_s[cb + 2] + sh_s[cb + 2], 0.f);
        v[3] = fmaxf(o0.w * sc_s[cb + 3] + sh_s[cb + 3], 0.f);
        v[4] = fmaxf(o1.x * sc_s[cb + 4] + sh_s[cb + 4], 0.f);
        v[5] = fmaxf(o1.y * sc_s[cb + 5] + sh_s[cb + 5], 0.f);
        v[6] = fmaxf(o1.z * sc_s[cb + 6] + sh_s[cb + 6], 0.f);
        v[7] = fmaxf(o1.w * sc_s[cb + 7] + sh_s[cb + 7], 0.f);
        if (ADD) {
            const float4* hp = (const float4*)(hA + (size_t)ar * 128 + cb);
            float4 h0 = hp[0], h1 = hp[1];
            v[0] += h0.x; v[1] += h0.y; v[2] += h0.z; v[3] += h0.w;
            v[4] += h1.x; v[5] += h1.y; v[6] += h1.z; v[7] += h1.w;
        }
        if (owner) {
            float4* hw = (float4*)(hA + (size_t)ar * 128 + cb);
            hw[0] = make_float4(v[0], v[1], v[2], v[3]);
            hw[1] = make_float4(v[4], v[5], v[6], v[7]);
        }
        uint4 pk;
        pk.x = bf16pair(v[0], v[1]); pk.y = bf16pair(v[2], v[3]);
        pk.z = bf16pair(v[4], v[5]); pk.w = bf16pair(v[6], v[7]);
        short8 afrag = *(short8*)&pk;
#pragma unroll
        for (int nt = 0; nt < 8; nt++) {
            short8 bfrag = wb8[(kt * 8 + nt) * 64 + lane];
            acc[nt] = __builtin_amdgcn_mfma_f32_16x16x32_bf16(afrag, bfrag, acc[nt], 0, 0, 0);
        }
    }

#pragma unroll
    for (int nt = 0; nt < 8; nt++)
#pragma unroll
        for (int rr = 0; rr < 4; rr++)
            lds[w][quad * 4 + rr][nt * 16 + mrow] = acc[nt][rr];

    int row = lane >> 2, h = lane & 3;
    int r = rbase + row;
    float vals[32];
    float ps = 0.f, pd = 0.f;
#pragma unroll
    for (int c = 0; c < 32; c++) {
        float v = lds[w][row][h * 32 + c];
        vals[c] = v;
        ps += v * att_s[h * 32 + c];
        pd += v * att_d[h * 32 + c];
    }
    if (r < N_NODES) {
        unsigned* dstp = xpb + (size_t)r * 64 + h * 16;
#pragma unroll
        for (int qq = 0; qq < 4; qq++) {
            uint4 o;
            o.x = bf16pair(vals[qq * 8 + 0], vals[qq * 8 + 1]);
            o.y = bf16pair(vals[qq * 8 + 2], vals[qq * 8 + 3]);
            o.z = bf16pair(vals[qq * 8 + 4], vals[qq * 8 + 5]);
            o.w = bf16pair(vals[qq * 8 + 6], vals[qq * 8 + 7]);
            ((uint4*)dstp)[qq] = o;
        }
        asrc[r * 4 + h] = ps;
        adst[r * 4 + h] = pd;
    }
}

// ---------------------------------------------------------------------------
// Single-pass aggregation with on-the-fly softmax weights.
// ---------------------------------------------------------------------------
__launch_bounds__(256)
__global__ void node_kernel(const uint2* __restrict__ aecsr, const float* __restrict__ asrc,
                            const float* __restrict__ adst, const int* __restrict__ rowp,
                            const int2* __restrict__ csr, const unsigned* __restrict__ xpb,
                            float* __restrict__ out) {
    int gw = (blockIdx.x * blockDim.x + threadIdx.x) >> 6;
    int lane = threadIdx.x & 63;
    if (gw >= N_NODES) return;
    int sub = lane >> 4;
    int sl  = lane & 15;
    int h   = sl >> 2;
    int beg = rowp[gw], end = rowp[gw + 1];
    const uint4* xp4 = (const uint4*)xpb;
    float adh = adst[gw * 4 + h];

    float a[8];
#pragma unroll
    for (int c = 0; c < 8; c++) a[c] = 0.f;
    float den = 0.f;

#define PROC(JJ)                                                                 \
    {                                                                            \
        int2 se = csr[JJ];                                                       \
        uint2 ae = aecsr[JJ];                                                    \
        unsigned aw = (h & 2) ? ae.y : ae.x;                                     \
        float aeh = __uint_as_float((h & 1) ? (aw & 0xFFFF0000u) : (aw << 16));  \
        float ash = asrc[se.x * 4 + h];                                          \
        uint4 v = xp4[(size_t)se.x * 16 + sl];                                   \
        float lg = ash + adh + aeh;                                              \
        lg = (lg > 0.f) ? lg : 0.2f * lg;                                        \
        float ex = __expf(fminf(lg, 60.f));                                      \
        a[0] += ex * __uint_as_float(v.x << 16);                                 \
        a[1] += ex * __uint_as_float(v.x & 0xFFFF0000u);                         \
        a[2] += ex * __uint_as_float(v.y << 16);                                 \
        a[3] += ex * __uint_as_float(v.y & 0xFFFF0000u);                         \
        a[4] += ex * __uint_as_float(v.z << 16);                                 \
        a[5] += ex * __uint_as_float(v.z & 0xFFFF0000u);                         \
        a[6] += ex * __uint_as_float(v.w << 16);                                 \
        a[7] += ex * __uint_as_float(v.w & 0xFFFF0000u);                         \
        den += ex;                                                               \
    }

    int j = beg + sub;
    for (; j + 12 < end; j += 16) {
        PROC(j); PROC(j + 4); PROC(j + 8); PROC(j + 12);
    }
    for (; j < end; j += 4) PROC(j);
#undef PROC

#pragma unroll
    for (int c = 0; c < 8; c++) {
        a[c] += __shfl_xor(a[c], 16);
        a[c] += __shfl_xor(a[c], 32);
    }
    den += __shfl_xor(den, 16);
    den += __shfl_xor(den, 32);
    float inv = 1.0f / den;
    if (sub == 0) {
        float* op = out + (size_t)gw * 128 + sl * 8;
        ((float4*)op)[0] = make_float4(a[0] * inv, a[1] * inv, a[2] * inv, a[3] * inv);
        ((float4*)op)[1] = make_float4(a[4] * inv, a[5] * inv, a[6] * inv, a[7] * inv);
    }
}

// ---------------------------------------------------------------------------
// BatchNorm statistics; final-layer standalone update (writes outp).
// ---------------------------------------------------------------------------
__launch_bounds__(256)
__global__ void bnstats_kernel(const float* __restrict__ h, float* __restrict__ bnsum,
                               float* __restrict__ bnsum2) {
    __shared__ float ls[256], ls2[256];
    int t = threadIdx.x;
    int c = t & 127, half = t >> 7;
    int r0 = blockIdx.x * 128;
    float s = 0.f, s2 = 0.f;
    int rend = min(r0 + 128, N_NODES);
    for (int r = r0 + half; r < rend; r += 2) {
        float v = h[(size_t)r * 128 + c];
        s += v; s2 += v * v;
    }
    ls[t] = s; ls2[t] = s2;
    __syncthreads();
    if (half == 0) {
        s += ls[t + 128]; s2 += ls2[t + 128];
        atomicAdd(&bnsum[c], s);
        atomicAdd(&bnsum2[c], s2);
    }
}

__launch_bounds__(256)
__global__ void finalupd_kernel(const float* __restrict__ outb, const float* __restrict__ bnsum,
                                const float* __restrict__ bnsum2, const float* __restrict__ gamma,
                                const float* __restrict__ beta, const float* __restrict__ hA,
                                float* __restrict__ dst) {
    __shared__ float sc_s[128], sh_s[128];
    int t = threadIdx.x;
    if (t < 128) {
        float mu = bnsum[t] / (float)N_NODES;
        float var = bnsum2[t] / (float)N_NODES - mu * mu;
        float inv = rsqrtf(var + BN_EPS);
        float g = gamma[t] * inv;
        sc_s[t] = g;
        sh_s[t] = beta[t] - mu * g;
    }
    __syncthreads();
    int i = blockIdx.x * blockDim.x + t;
    if (i >= N_NODES * 32) return;
    int c4 = (i & 31) * 4;
    float4 o = ((const float4*)outb)[i];
    float4 hh = ((const float4*)hA)[i];
    float4 v;
    v.x = fmaxf(o.x * sc_s[c4 + 0] + sh_s[c4 + 0], 0.f) + hh.x;
    v.y = fmaxf(o.y * sc_s[c4 + 1] + sh_s[c4 + 1], 0.f) + hh.y;
    v.z = fmaxf(o.z * sc_s[c4 + 2] + sh_s[c4 + 2], 0.f) + hh.z;
    v.w = fmaxf(o.w * sc_s[c4 + 3] + sh_s[c4 + 3], 0.f) + hh.w;
    ((float4*)dst)[i] = v;
}

// ---------------------------------------------------------------------------
extern "C" void kernel_launch(void* const* d_in, const int* in_sizes, int n_in,
                              void* d_out, int out_size, void* d_ws, size_t ws_size,
                              hipStream_t stream) {
    const float* x          = (const float*)d_in[0];
    const int*   edge_index = (const int*)d_in[1];
    const float* edge_attr  = (const float*)d_in[2];
    const float* Wp         = (const float*)d_in[3];
    const float* bp         = (const float*)d_in[4];
    const float* W          = (const float*)d_in[5];
    const float* We         = (const float*)d_in[6];
    const float* att_src    = (const float*)d_in[7];
    const float* att_dst    = (const float*)d_in[8];
    const float* att_edge   = (const float*)d_in[9];
    // d_in[10] bias: absorbed exactly by training-mode BN -> skipped
    const float* gamma      = (const float*)d_in[11];
    const float* beta       = (const float*)d_in[12];
    float* outp = (float*)d_out;

    const int* ei_src = edge_index;
    const int* ei_dst = edge_index + N_EDGES;

    char* p = (char*)d_ws;
    auto alloc = [&](size_t nbytes) {
        char* r = p;
        p += (nbytes + 255) & ~(size_t)255;
        return r;
    };
    // zero-initialized region: easum | bnsum(4 layers x 256)
    float* easum    = (float*)alloc(16 * 4);
    float* bnsumall = (float*)alloc((size_t)LAYERS * 256 * 4);
    size_t zero_bytes = (char*)(bnsumall + LAYERS * 256) - (char*)easum;

    float* hA       = (float*)alloc((size_t)N_NODES * 128 * 4);
    unsigned* hAb   = (unsigned*)alloc((size_t)N_NODES * 64 * 4);   // bf16x2 (layer-0 A feed)
    unsigned* xpb   = (unsigned*)alloc((size_t)N_NODES * 64 * 4);   // bf16x2 gather payload
    float* outb     = (float*)alloc((size_t)N_NODES * 128 * 4);
    float* asrc     = (float*)alloc((size_t)N_NODES * 4 * 4);
    float* adst     = (float*)alloc((size_t)N_NODES * 4 * 4);
    float* wea_all  = (float*)alloc((LAYERS * 48 + 16) * 4);
    float* aloop    = wea_all + LAYERS * 48;
    unsigned short* wb = (unsigned short*)alloc((size_t)LAYERS * 16384 * 2);
    int* rowp       = (int*)alloc(((size_t)N_NODES + 1) * 4);
    int* counts     = (int*)alloc((size_t)F_TOT * 4);
    int* chunkbase  = (int*)alloc(((size_t)F_TOT + 1) * 4);
    int2* bucketed  = (int2*)alloc((size_t)N_ETOT * 8);
    int2* csr       = (int2*)alloc((size_t)N_ETOT * 8);
    uint2* aecsr    = (uint2*)alloc((size_t)LAYERS * N_ETOT * 8);
    int* bsum       = (int*)alloc(1024 * 4);
    int* boff       = (int*)alloc(1024 * 4);

    (void)hipMemsetAsync(easum, 0, zero_bytes, stream);

    // ---- preamble: counting-sort CSR build + folded matrices + W pack + gemm0 ----
    pre1_kernel<<<GB + NCHUNK + 256 + WB, 256, 0, stream>>>(
        ei_dst, counts, edge_attr, easum, W, wb, x, Wp, bp, hA, hAb);
    blocksum2_kernel<<<SB3, 256, 0, stream>>>(counts, bsum);
    pre2_kernel<<<2, 256, 0, stream>>>(bsum, boff, chunkbase, rowp, easum, We, att_edge,
                                       wea_all, aloop);
    addback_kernel<<<SB3, 256, 0, stream>>>(counts, boff, chunkbase);
    pre3_kernel<<<GB + NCHUNK, 256, 0, stream>>>(
        (const unsigned short*)hAb, wb, att_src, att_dst, xpb, asrc, adst,
        ei_src, ei_dst, chunkbase, bucketed);
    csrd_kernel<<<NB, 256, 0, stream>>>(bucketed, chunkbase, csr, rowp);
    pre4_kernel<<<EB, 256, 0, stream>>>(csr, edge_attr, wea_all, aloop, aecsr);

    for (int l = 0; l < LAYERS; l++) {
        float* bnsum  = bnsumall + l * 256;
        float* bnsum2 = bnsum + 128;
        node_kernel<<<(N_NODES + 3) / 4, 256, 0, stream>>>(
            aecsr + (size_t)l * N_ETOT, asrc, adst, rowp, csr, xpb, outb);
        bnstats_kernel<<<(N_NODES + 127) / 128, 256, 0, stream>>>(outb, bnsum, bnsum2);
        if (l < LAYERS - 1) {
            // fused: h_{l+1} = relu(bn_l(outb)) (+ hA if l>0) -> hA, A-frag in-reg
            if (l == 0)
                gemm_fused_kernel<0><<<GB, 256, 0, stream>>>(
                    outb, bnsum, bnsum2, gamma + l * 128, beta + l * 128, hA,
                    wb + (size_t)(l + 1) * 16384, att_src + (l + 1) * 128,
                    att_dst + (l + 1) * 128, xpb, asrc, adst);
            else
                gemm_fused_kernel<1><<<GB, 256, 0, stream>>>(
                    outb, bnsum, bnsum2, gamma + l * 128, beta + l * 128, hA,
                    wb + (size_t)(l + 1) * 16384, att_src + (l + 1) * 128,
                    att_dst + (l + 1) * 128, xpb, asrc, adst);
        } else {
            finalupd_kernel<<<(N_NODES * 32 + 255) / 256, 256, 0, stream>>>(
                outb, bnsum, bnsum2, gamma + l * 128, beta + l * 128, hA, outp);
        }
    }
}